// Round 12
// baseline (669.148 us; speedup 1.0000x reference)
//
#include <hip/hip_runtime.h>
#include <hip/hip_bf16.h>
#include <cstdint>

// ---------------------------------------------------------------------------
// SquashedGaussianMoEActor forward, MI355X (gfx950).
// Split-f16 MFMA = fp32-quality on the score path (softmax smoothness
// analysis: score error must stay <<0.05 abs); single-f16 tower path
// (error budget verified: absmax 4.0 vs threshold 14.56, R6-R11).
// R12: consolidation -- Rcat single-f16, 5 fewer dispatches (merged splits/
// transposes/folds, scores_init->memset+softmax), 6 blk/CU on single-plane
// GEMMs. passA (250us @ 37% MfmaUtil, XCD-swizzled) untouched.
// B=8192, OBS=128, H=D=512, E=16, T=50, A=32.
// ---------------------------------------------------------------------------

typedef _Float16 f16;
typedef _Float16 f16x4 __attribute__((ext_vector_type(4)));
typedef _Float16 f16x8 __attribute__((ext_vector_type(8)));
typedef float f32x4 __attribute__((ext_vector_type(4)));

__device__ __forceinline__ void fsplit(float x, f16& h, f16& l) {
    h = (f16)x;
    l = (f16)(x - (float)h);
}

__device__ __forceinline__ void gload16(const void* g, void* s) {
    __builtin_amdgcn_global_load_lds(
        (const __attribute__((address_space(1))) void*)g,
        (__attribute__((address_space(3))) void*)s, 16, 0, 0);
}

// --- elementwise fp32 -> f16 pair split -----------------------------------
__global__ void split_pairs(const float* __restrict__ x, f16* __restrict__ h,
                            f16* __restrict__ l, int n4) {
    int i = blockIdx.x * 256 + threadIdx.x;
    if (i >= n4) return;
    float4 v = ((const float4*)x)[i];
    float a[4] = {v.x, v.y, v.z, v.w};
    f16x4 hh, ll;
#pragma unroll
    for (int j = 0; j < 4; ++j) { f16 hj, lj; fsplit(a[j], hj, lj); hh[j] = hj; ll[j] = lj; }
    *(f16x4*)&h[(long)i * 4] = hh;
    *(f16x4*)&l[(long)i * 4] = ll;
}

// --- eW2 + keyM + obs splits in one dispatch -------------------------------
__global__ void split_pairs3(const float* __restrict__ xa, f16* __restrict__ ha,
                             f16* __restrict__ la, const float* __restrict__ xb,
                             f16* __restrict__ hb, f16* __restrict__ lb,
                             const float* __restrict__ xc, f16* __restrict__ hc,
                             f16* __restrict__ lc) {
    long i = (long)blockIdx.x * 256 + threadIdx.x;  // grid 9216 -> 2359296
    const float* x; f16* h; f16* l;
    if (i < 1048576) { x = xa; h = ha; l = la; }
    else if (i < 2097152) { i -= 1048576; x = xb; h = hb; l = lb; }
    else { i -= 2097152; x = xc; h = hc; l = lc; }
    float4 v = ((const float4*)x)[i];
    float a[4] = {v.x, v.y, v.z, v.w};
    f16x4 hh, ll;
#pragma unroll
    for (int j = 0; j < 4; ++j) { f16 hj, lj; fsplit(a[j], hj, lj); hh[j] = hj; ll[j] = lj; }
    *(f16x4*)&h[i * 4] = hh;
    *(f16x4*)&l[i * 4] = ll;
}

// --- six weight transposes in one dispatch (z = 0..35) ---------------------
// z<16: eW1_e, z<32: valM_e, 32: bW2, 33: mW1, 34: lW1, 35: bW1 (K=128).
__global__ void transpose_split6(
    const float* __restrict__ eW1, const float* __restrict__ valM,
    const float* __restrict__ bW2, const float* __restrict__ mW1,
    const float* __restrict__ lW1, const float* __restrict__ bW1,
    f16* __restrict__ eW1t_h, f16* __restrict__ eW1t_l,
    f16* __restrict__ Vt_h, f16* __restrict__ Vt_l,
    f16* __restrict__ bW2t_h, f16* __restrict__ bW2t_l,
    f16* __restrict__ mW1t_h, f16* __restrict__ mW1t_l,
    f16* __restrict__ lW1t_h, f16* __restrict__ lW1t_l,
    f16* __restrict__ bW1t_h, f16* __restrict__ bW1t_l) {
    __shared__ float t[32][33];
    const int z = blockIdx.z;
    const float* W; f16* Th; f16* Tl; int Kd = 512;
    if (z < 16) { W = eW1 + (long)z * 262144; Th = eW1t_h + (long)z * 262144; Tl = eW1t_l + (long)z * 262144; }
    else if (z < 32) { const int e = z - 16; W = valM + (long)e * 262144; Th = Vt_h + (long)e * 262144; Tl = Vt_l + (long)e * 262144; }
    else if (z == 32) { W = bW2; Th = bW2t_h; Tl = bW2t_l; }
    else if (z == 33) { W = mW1; Th = mW1t_h; Tl = mW1t_l; }
    else if (z == 34) { W = lW1; Th = lW1t_h; Tl = lW1t_l; }
    else { W = bW1; Th = bW1t_h; Tl = bW1t_l; Kd = 128; if (blockIdx.x >= 4) return; }
    const int k0 = blockIdx.x * 32, n0 = blockIdx.y * 32;
    const int tid = threadIdx.x;
    const int r = tid >> 3, c4 = (tid & 7) * 4;
    float4 v = *(const float4*)&W[(long)(k0 + r) * 512 + n0 + c4];
    t[r][c4] = v.x; t[r][c4 + 1] = v.y; t[r][c4 + 2] = v.z; t[r][c4 + 3] = v.w;
    __syncthreads();
    f16x4 hh, ll;
#pragma unroll
    for (int j = 0; j < 4; ++j) { f16 hj, lj; fsplit(t[c4 + j][r], hj, lj); hh[j] = hj; ll[j] = lj; }
    const long ob = (long)(n0 + r) * Kd + k0 + c4;
    *(f16x4*)&Th[ob] = hh;
    *(f16x4*)&Tl[ob] = ll;
}

// --- W2T[half][col][k] + bcat = [mb1;lb1] in one dispatch ------------------
__global__ void build_w2t_bcat(const float* __restrict__ mW2, const float* __restrict__ lW2,
                               const float* __restrict__ mb1, const float* __restrict__ lb1,
                               float* __restrict__ W2T, float* __restrict__ bcat) {
    const int i = blockIdx.x * 256 + threadIdx.x;  // grid 132 -> 33792
    if (i < 32768) {
        const int half = i >> 14, col = (i >> 9) & 31, k = i & 511;
        const float* src = half ? lW2 : mW2;
        W2T[i] = src[k * 32 + col];
    } else {
        const int j = i - 32768;
        if (j < 1024) bcat[j] = (j < 512) ? mb1[j] : lb1[j - 512];
    }
}

// --- b2V fold + cb-from-Kq in one dispatch ---------------------------------
__global__ void fold_misc(const float* __restrict__ eb2, const float* __restrict__ valM,
                          const f16* __restrict__ KqT_h, const f16* __restrict__ KqT_l,
                          float* __restrict__ b2V, float* __restrict__ cb) {
    if (blockIdx.x < 32) {
        // b2V[e*512+j] = sum_k eb2[e,k] * valM[e][k][j]
        const int gid = blockIdx.x * 256 + threadIdx.x;  // 8192
        const int e = gid >> 9, j = gid & 511;
        const float* Me = valM + (long)e * 262144;
        const float* be = eb2 + e * 512;
        float s = 0.f;
        for (int k = 0; k < 512; ++k) s += be[k] * Me[(long)k * 512 + j];
        b2V[gid] = s;
    } else {
        // cb[t][e] = sum_k eb2[e,k] * Kq[e,k,t]
        const int gw = ((blockIdx.x - 32) * 256 + threadIdx.x) >> 6;  // 0..799
        const int l = threadIdx.x & 63;
        const int t = gw >> 4, e = gw & 15;
        const long base = (long)t * 8192 + e * 512 + l * 8;
        f16x8 hh = *(const f16x8*)&KqT_h[base];
        f16x8 ll = *(const f16x8*)&KqT_l[base];
        const float* bb = eb2 + e * 512 + l * 8;
        float s = 0.f;
#pragma unroll
        for (int j = 0; j < 8; ++j) s += ((float)hh[j] + (float)ll[j]) * bb[j];
#pragma unroll
        for (int d = 1; d < 64; d <<= 1) s += __shfl_xor(s, d);
        if (l == 0) cb[t * 16 + e] = s;
    }
}

// --- split-f16 GEMM: C = act(A @ B^T_stored + bias) ------------------------
// Tile 64x128, BK=64, 4 waves each owning 32x64 (2x4 frags of 16x16x32).
// Staging via global_load_lds (linear LDS dest, pre-swizzled global source;
// read side applies the same chunk^=row&7 involution). Single-buffered,
// 3-6 blocks/CU -- inter-block overlap hides barrier drains (m114).
// OUTM: 0 pair write, 1 pair write transposed, 2 f32 write, 3 f32 accum,
//       5 score mode (flat expert=col0>>9; XCD y-chunk swizzle; row-dot KQ2
//         -> atomicAdd) + write t1 single-f16 to Ch (U), 6 f32 transposed,
//       7 single-f16 write transposed, 8 single-f16 write w/ f32 C-in (Cf),
//       9 single-f16 plain write.
// AMODE: 0 = A pair (gload, 3rd MFMA), 1 = A single (gload),
//        2 = A single reg-staged with fused per-(row, k-block) wscale.
// BSINGLE: B single plane (skips the AhBl MFMA).
template <int OUTM, bool RELU, int AMODE, bool BSINGLE>
__global__ __launch_bounds__(256, (AMODE == 0 && !BSINGLE) ? 3 : (AMODE == 0 ? 4 : 6))
void gemm_pair(
    const f16* __restrict__ Ah, const f16* __restrict__ Al, int lda, long zsA,
    const f16* __restrict__ Bh, const f16* __restrict__ Bl, int ldb, long zsB,
    const float* __restrict__ bias, long zsBias,
    f16* __restrict__ Ch, f16* __restrict__ Cl, float* __restrict__ Cf,
    int ldc, long zsC, int K,
    const float* __restrict__ wscale,
    const int* __restrict__ task, const float* __restrict__ KQ2,
    float* __restrict__ scores) {
    __shared__ f16 As[AMODE == 0 ? 2 : 1][64][64];
    __shared__ f16 Bs[BSINGLE ? 1 : 2][128][64];
    const int z = blockIdx.z;
    Ah += (long)z * zsA;
    if constexpr (AMODE == 0) Al += (long)z * zsA;
    Bh += (long)z * zsB;
    if constexpr (!BSINGLE) Bl += (long)z * zsB;
    if (bias) bias += (long)z * zsBias;
    if (OUTM <= 1) { Ch += (long)z * zsC; Cl += (long)z * zsC; }
    if (OUTM == 7 || OUTM == 9) { Ch += (long)z * zsC; }
    if (OUTM == 2 || OUTM == 3 || OUTM == 6) { Cf += (long)z * zsC; }
    const int tid = threadIdx.x;
    const int l = tid & 63;
    const int w = tid >> 6;
    int bx = blockIdx.x, by = blockIdx.y;
    if constexpr (OUTM == 5) {
        // XCD y-chunk swizzle (R10-verified): grid (128,64); each XCD owns 8
        // contiguous col-tiles -> its B pair working set stays L2-resident.
        const int id = by * gridDim.x + bx;
        const int xcd = id & 7, r = id >> 3;
        by = (xcd << 3) | (r & 7);
        bx = r >> 3;
    }
    const int row0 = bx * 64;
    const int col0 = by * 128;
    const int wr = (w >> 1) * 32;
    const int wc = (w & 1) * 64;
    const int grow = l >> 3;           // row within 8-row group
    const int gch = (l & 7) ^ grow;    // pre-swizzled k-chunk for gload_lds

    f32x4 acc[2][4];
#pragma unroll
    for (int mi = 0; mi < 2; ++mi)
#pragma unroll
        for (int ni = 0; ni < 4; ++ni)
#pragma unroll
            for (int j = 0; j < 4; ++j) acc[mi][ni][j] = 0.f;

    // AMODE==2: reg-staged A with fused per-(row, k-block) scale
    uint4 areg0, areg1; float ascl0, ascl1;
    auto ldA = [&](int k0) {
        const int r0 = w * 16 + grow, r1 = r0 + 8;
        const int scl = l & 7;
        areg0 = *(const uint4*)&Ah[(long)(row0 + r0) * lda + k0 + scl * 8];
        areg1 = *(const uint4*)&Ah[(long)(row0 + r1) * lda + k0 + scl * 8];
        const int e = k0 >> 9;
        ascl0 = wscale[(long)(row0 + r0) * 16 + e];
        ascl1 = wscale[(long)(row0 + r1) * 16 + e];
    };
    auto wrA = [&]() {
        const int scl = l & 7;
#pragma unroll
        for (int h = 0; h < 2; ++h) {
            const int r = w * 16 + grow + h * 8;
            const float s = h ? ascl1 : ascl0;
            f16x8 v = h ? *(f16x8*)&areg1 : *(f16x8*)&areg0;
#pragma unroll
            for (int j = 0; j < 8; ++j) v[j] = (f16)((float)v[j] * s);
            *(uint4*)&As[0][r][(scl ^ (r & 7)) * 8] = *(uint4*)&v;
        }
    };

    if constexpr (AMODE == 2) ldA(0);
    for (int k0 = 0; k0 < K; k0 += 64) {
        __syncthreads();
        if constexpr (AMODE == 2) {
            wrA();
            if (k0 + 64 < K) ldA(k0 + 64);  // next loads issued early (hidden under compute)
        } else {
            // A: wave w stages rows [w*16, w*16+16)
            const long ga = (long)(row0 + w * 16 + grow) * lda + k0 + gch * 8;
            gload16(Ah + ga, &As[0][w * 16][0]);
            gload16(Ah + ga + (long)8 * lda, &As[0][w * 16 + 8][0]);
            if constexpr (AMODE == 0) {
                gload16(Al + ga, &As[1][w * 16][0]);
                gload16(Al + ga + (long)8 * lda, &As[1][w * 16 + 8][0]);
            }
        }
        {
            // B: wave w stages rows [w*32, w*32+32)
            const long gb = (long)(col0 + w * 32 + grow) * ldb + k0 + gch * 8;
            gload16(Bh + gb, &Bs[0][w * 32][0]);
            gload16(Bh + gb + (long)8 * ldb, &Bs[0][w * 32 + 8][0]);
            gload16(Bh + gb + (long)16 * ldb, &Bs[0][w * 32 + 16][0]);
            gload16(Bh + gb + (long)24 * ldb, &Bs[0][w * 32 + 24][0]);
            if constexpr (!BSINGLE) {
                gload16(Bl + gb, &Bs[1][w * 32][0]);
                gload16(Bl + gb + (long)8 * ldb, &Bs[1][w * 32 + 8][0]);
                gload16(Bl + gb + (long)16 * ldb, &Bs[1][w * 32 + 16][0]);
                gload16(Bl + gb + (long)24 * ldb, &Bs[1][w * 32 + 24][0]);
            }
        }
        __syncthreads();
        const int r16 = l & 15, kg = l >> 4;
#pragma unroll
        for (int ks = 0; ks < 2; ++ks) {
            f16x8 a_h[2], a_l[2], b_h[4], b_l[4];
#pragma unroll
            for (int mi = 0; mi < 2; ++mi) {
                const int r = wr + mi * 16 + r16;
                const int off = ((ks * 4 + kg) ^ (r & 7)) * 8;
                a_h[mi] = *(const f16x8*)&As[0][r][off];
                if constexpr (AMODE == 0) a_l[mi] = *(const f16x8*)&As[1][r][off];
            }
#pragma unroll
            for (int ni = 0; ni < 4; ++ni) {
                const int c = wc + ni * 16 + r16;
                const int off = ((ks * 4 + kg) ^ (c & 7)) * 8;
                b_h[ni] = *(const f16x8*)&Bs[0][c][off];
                if constexpr (!BSINGLE) b_l[ni] = *(const f16x8*)&Bs[1][c][off];
            }
#pragma unroll
            for (int mi = 0; mi < 2; ++mi)
#pragma unroll
                for (int ni = 0; ni < 4; ++ni) {
                    acc[mi][ni] = __builtin_amdgcn_mfma_f32_16x16x32_f16(a_h[mi], b_h[ni], acc[mi][ni], 0, 0, 0);
                    if constexpr (!BSINGLE)
                        acc[mi][ni] = __builtin_amdgcn_mfma_f32_16x16x32_f16(a_h[mi], b_l[ni], acc[mi][ni], 0, 0, 0);
                    if constexpr (AMODE == 0)
                        acc[mi][ni] = __builtin_amdgcn_mfma_f32_16x16x32_f16(a_l[mi], b_h[ni], acc[mi][ni], 0, 0, 0);
                }
        }
    }
    // epilogue. C layout (m89-verified): col = lane&15, row = (lane>>4)*4 + reg.
    const int lane15 = l & 15;
    const int rsub = (l >> 4) * 4;
    if (OUTM == 5) {
        const int expert = col0 >> 9;
        float bv[4];
#pragma unroll
        for (int ni = 0; ni < 4; ++ni)
            bv[ni] = bias ? bias[col0 + wc + ni * 16 + lane15] : 0.f;
#pragma unroll
        for (int mi = 0; mi < 2; ++mi)
#pragma unroll
            for (int j = 0; j < 4; ++j) {
                const int rowg = row0 + wr + mi * 16 + rsub + j;
                const int t = task[rowg];
                const float* kqr = KQ2 + ((long)t * 16 + expert) * 512;
                float part = 0.f;
#pragma unroll
                for (int ni = 0; ni < 4; ++ni) {
                    const int colg = col0 + wc + ni * 16 + lane15;
                    float v = acc[mi][ni][j] + bv[ni];
                    if (RELU) v = fmaxf(v, 0.f);
                    Ch[(long)rowg * ldc + colg] = (f16)v;
                    part += v * kqr[colg & 511];
                }
#pragma unroll
                for (int d = 1; d < 16; d <<= 1) part += __shfl_xor(part, d);
                if (lane15 == 0) atomicAdd(&scores[rowg * 16 + expert], part);
            }
    } else {
#pragma unroll
        for (int mi = 0; mi < 2; ++mi)
#pragma unroll
            for (int ni = 0; ni < 4; ++ni) {
                const int colg = col0 + wc + ni * 16 + lane15;
                const float bv = bias ? bias[colg] : 0.f;
#pragma unroll
                for (int j = 0; j < 4; ++j) {
                    const int rowg = row0 + wr + mi * 16 + rsub + j;
                    float v = acc[mi][ni][j] + bv;
                    if (RELU) v = fmaxf(v, 0.f);
                    if (OUTM == 0) {
                        f16 hh, ll; fsplit(v, hh, ll);
                        const long idx = (long)rowg * ldc + colg;
                        Ch[idx] = hh; Cl[idx] = ll;
                    } else if (OUTM == 1) {
                        f16 hh, ll; fsplit(v, hh, ll);
                        const long idx = (long)colg * ldc + rowg;
                        Ch[idx] = hh; Cl[idx] = ll;
                    } else if (OUTM == 2) {
                        Cf[(long)rowg * ldc + colg] = v;
                    } else if (OUTM == 3) {
                        Cf[(long)rowg * ldc + colg] += v;
                    } else if (OUTM == 6) {
                        Cf[(long)colg * ldc + rowg] = v;
                    } else if (OUTM == 7) {
                        Ch[(long)colg * ldc + rowg] = (f16)v;
                    } else if (OUTM == 8) {
                        const long idx = (long)rowg * ldc + colg;
                        v += Cf[idx];   // wb input
                        Ch[idx] = (f16)v;
                    } else if (OUTM == 9) {
                        Ch[(long)rowg * ldc + colg] = (f16)v;
                    }
                }
            }
    }
}

// --- softmax over E=16 per row; adds cb[task[b]] (scores pre-zeroed) -------
__global__ void softmax16(float* __restrict__ sc, const int* __restrict__ task,
                          const float* __restrict__ cb) {
    const int b = blockIdx.x * 256 + threadIdx.x;  // 8192
    const float* cbr = cb + task[b] * 16;
    float v[16];
    const float4* pp = (const float4*)&sc[b * 16];
    const float4* cp = (const float4*)cbr;
#pragma unroll
    for (int qq = 0; qq < 4; ++qq) {
        float4 t = pp[qq];
        float4 c = cp[qq];
        v[qq * 4] = t.x + c.x; v[qq * 4 + 1] = t.y + c.y;
        v[qq * 4 + 2] = t.z + c.z; v[qq * 4 + 3] = t.w + c.w;
    }
    float m = v[0];
#pragma unroll
    for (int e = 1; e < 16; ++e) m = fmaxf(m, v[e]);
    float ssum = 0.f;
#pragma unroll
    for (int e = 0; e < 16; ++e) { v[e] = expf(v[e] - m); ssum += v[e]; }
    const float inv = 1.f / ssum;
    float4* o = (float4*)&sc[b * 16];
#pragma unroll
    for (int qq = 0; qq < 4; ++qq) {
        float4 t;
        t.x = v[qq * 4] * inv; t.y = v[qq * 4 + 1] * inv;
        t.z = v[qq * 4 + 2] * inv; t.w = v[qq * 4 + 3] * inv;
        o[qq] = t;
    }
}

// --- towerAcc[b][j] = sum_e w[b][e] * b2V[e][j] ----------------------------
__global__ void wb_init(const float* __restrict__ w, const float* __restrict__ b2V,
                        float* __restrict__ towerAcc) {
    const int b = blockIdx.x;
    const int tid = threadIdx.x;
    float wv[16];
#pragma unroll
    for (int e = 0; e < 16; ++e) wv[e] = w[b * 16 + e];
#pragma unroll
    for (int rep = 0; rep < 2; ++rep) {
        const int j = rep * 256 + tid;
        float s = 0.f;
#pragma unroll
        for (int e = 0; e < 16; ++e) s += wv[e] * b2V[e * 512 + j];
        towerAcc[(long)b * 512 + j] = s;
    }
}

// --- final heads: GEMV vs W2T (float4 streams), squash, logp ---------------
// Rcat: [8192][1024] single f16; cols 0..511 = mu path, 512..1023 = ls path.
__global__ void head_kernel2(
    const f16* __restrict__ Rh,
    const float* __restrict__ W2T,   // [2][32][512]
    const float* __restrict__ mb2, const float* __restrict__ lb2,
    const float* __restrict__ eps, float* __restrict__ pi, float* __restrict__ logp) {
    __shared__ float src[4][1032];
    const int tid = threadIdx.x, l = tid & 63, w = tid >> 6;
    const int b = blockIdx.x * 4 + w;  // one wave per row
    const long rb = (long)b * 1024;
    {
        f16x8 h0 = *(const f16x8*)&Rh[rb + l * 8];
        f16x8 h1 = *(const f16x8*)&Rh[rb + 512 + l * 8];
#pragma unroll
        for (int j = 0; j < 8; ++j) {
            src[w][l * 8 + j] = (float)h0[j];
            src[w][512 + l * 8 + j] = (float)h1[j];
        }
    }
    __syncthreads();
    const int col = l & 31;
    const int half = l >> 5;  // 0 = mu, 1 = log_std
    const float4* wp = (const float4*)(W2T + ((long)(half * 32 + col)) * 512);
    const float4* sp = (const float4*)(&src[w][half * 512]);
    float a0 = 0.f, a1 = 0.f, a2 = 0.f, a3 = 0.f;
#pragma unroll 8
    for (int k4 = 0; k4 < 128; ++k4) {
        const float4 wv = wp[k4];
        const float4 sv = sp[k4];
        a0 = fmaf(wv.x, sv.x, a0);
        a1 = fmaf(wv.y, sv.y, a1);
        a2 = fmaf(wv.z, sv.z, a2);
        a3 = fmaf(wv.w, sv.w, a3);
    }
    const float* b2 = half ? lb2 : mb2;
    float s = b2[col] + ((a0 + a1) + (a2 + a3));
    const float other = __shfl_xor(s, 32);  // swap mu <-> log_std halves
    if (half == 0) {
        const float mu = s;
        float ls = fminf(fmaxf(other, -20.f), 2.f);
        const float e = eps[(long)b * 32 + col];
        const float a = mu + expf(ls) * e;
        float lt = -0.5f * e * e - ls - 0.91893853320467274f;  // -0.5*log(2*pi)
        const float x = -2.f * a;
        const float sp2 = fmaxf(x, 0.f) + log1pf(expf(-fabsf(x)));
        lt -= 2.f * (0.69314718055994531f - a - sp2);
        pi[(long)b * 32 + col] = tanhf(a);
        float r = lt;
#pragma unroll
        for (int d = 1; d < 32; d <<= 1) r += __shfl_xor(r, d);
        if (col == 0) logp[b] = r;
    }
}

// ---------------------------------------------------------------------------
extern "C" void kernel_launch(void* const* d_in, const int* in_sizes, int n_in,
                              void* d_out, int out_size, void* d_ws, size_t ws_size,
                              hipStream_t stream) {
    const float* obs = (const float*)d_in[0];
    const int* task = (const int*)d_in[1];
    const float* eps = (const float*)d_in[2];
    const float* bW1 = (const float*)d_in[3];
    const float* bb1 = (const float*)d_in[4];
    const float* bW2 = (const float*)d_in[5];
    const float* bb2 = (const float*)d_in[6];
    const float* eW1 = (const float*)d_in[7];
    const float* eb1 = (const float*)d_in[8];
    const float* eW2 = (const float*)d_in[9];
    const float* eb2 = (const float*)d_in[10];
    const float* keyM = (const float*)d_in[11];
    const float* valM = (const float*)d_in[12];
    const float* tq = (const float*)d_in[13];
    const float* mW1 = (const float*)d_in[14];
    const float* mb1 = (const float*)d_in[15];
    const float* mW2 = (const float*)d_in[16];
    const float* mb2 = (const float*)d_in[17];
    const float* lW1 = (const float*)d_in[18];
    const float* lb1 = (const float*)d_in[19];
    const float* lW2 = (const float*)d_in[20];
    const float* lb2 = (const float*)d_in[21];
    (void)in_sizes; (void)n_in; (void)out_size; (void)ws_size;

    // ---- workspace map (base 122 MB + 128 MB U; ws >= 251 MB verified R4) --
    const size_t MB = 1u << 20, KB = 1u << 10;
    char* base = (char*)d_ws;
    f16* eW1t_h = (f16*)(base + 0 * MB);   f16* eW1t_l = (f16*)(base + 8 * MB);
    f16* Wv2_h  = (f16*)(base + 16 * MB);  // [j2][(e,i)] single f16
    f16* eW2s_h = (f16*)(base + 32 * MB);  f16* eW2s_l = (f16*)(base + 40 * MB);
    f16* h2_h   = (f16*)(base + 32 * MB);  f16* h2_l   = (f16*)(base + 40 * MB);  // after folds
    f16* t1_h   = (f16*)(base + 48 * MB);  f16* t1_l   = (f16*)(base + 56 * MB);
    f16* Rcat   = (f16*)(base + 48 * MB);                                         // heads (t1 dead), 16 MB single
    f16* Vt_h   = (f16*)(base + 64 * MB);  f16* Vt_l   = (f16*)(base + 72 * MB);
    // 80-112 MB region, phase 1 (KQ path): keyM pairs, KqT, tqP, KQ2
    f16* keyMs_h = (f16*)(base + 80 * MB); f16* keyMs_l = (f16*)(base + 88 * MB);
    f16* KqT_h   = (f16*)(base + 96 * MB); f16* KqT_l   = (f16*)(base + 98 * MB); // [128][8192]
    f16* tqP_h   = (f16*)(base + 100 * MB); f16* tqP_l  = (f16*)(base + 100 * MB + 128 * KB); // [128][512]
    float* KQ2   = (float*)(base + 104 * MB);                                     // [128][16][512] f32
    // 80-112 MB region, phase 2 (tower/heads): towerAcc (wb), twP (single)
    float* towerAcc = (float*)(base + 80 * MB);                                   // 16 MB
    f16* twP_h  = (f16*)(base + 96 * MB);
    f16* obs_h  = (f16*)(base + 112 * MB); f16* obs_l  = (f16*)(base + 114 * MB);
    char* q = base + 116 * MB;
    f16* bW1t_h = (f16*)q; q += 128 * KB;  f16* bW1t_l = (f16*)q; q += 128 * KB;
    f16* bW2t_h = (f16*)q; q += 512 * KB;  f16* bW2t_l = (f16*)q; q += 512 * KB;
    // order m_h, l_h, m_l, l_l so the z=2 head GEMM can stride (zsB = 262144)
    f16* mW1t_h = (f16*)q; q += 512 * KB;
    f16* lW1t_h = (f16*)q; q += 512 * KB;
    f16* mW1t_l = (f16*)q; q += 512 * KB;
    f16* lW1t_l = (f16*)q; q += 512 * KB;
    float* scores = (float*)q; q += 512 * KB;    // 8192*16 f32 (becomes w)
    float* b2V    = (float*)q; q += 32 * KB;
    float* cb     = (float*)q; q += 16 * KB;
    float* W2T    = (float*)q; q += 128 * KB;    // [2][32][512]
    float* bcat   = (float*)q; q += 16 * KB;     // [2][512]
    f16* U = (f16*)(base + 122 * MB);            // [8192][8192] single f16

    const long EST = 262144;  // per-expert 512x512 stride

    // ---- 1) splits / transposes ----
    hipMemsetAsync(tqP_h, 0, 256 * KB, stream);   // tqP_h and tqP_l contiguous
    hipMemsetAsync(scores, 0, 512 * KB, stream);  // passA atomicAdd target
    split_pairs3<<<9216, 256, 0, stream>>>(eW2, eW2s_h, eW2s_l, keyM, keyMs_h, keyMs_l,
                                           obs, obs_h, obs_l);
    split_pairs<<<25, 256, 0, stream>>>(tq, tqP_h, tqP_l, 6400);
    transpose_split6<<<dim3(16, 16, 36), 256, 0, stream>>>(
        eW1, valM, bW2, mW1, lW1, bW1, eW1t_h, eW1t_l, Vt_h, Vt_l,
        bW2t_h, bW2t_l, mW1t_h, mW1t_l, lW1t_h, lW1t_l, bW1t_h, bW1t_l);
    build_w2t_bcat<<<132, 256, 0, stream>>>(mW2, lW2, mb1, lb1, W2T, bcat);

    // ---- 2) attention folds ----
    // Wv2[j2][(e,i)] = (eW2@V)[i][j2]  (single-f16 out -> 2-MFMA: A pair x B single)
    gemm_pair<7, false, 0, true><<<dim3(8, 4, 16), 256, 0, stream>>>(
        eW2s_h, eW2s_l, 512, EST, Vt_h, nullptr, 512, EST, nullptr, 0,
        Wv2_h, nullptr, nullptr, 8192, 512, 512, nullptr, nullptr, nullptr, nullptr);
    // KqT[t][(e,k)] = (keyM @ tq^T)[(e,k)][t]   (N=128 padded, pair transposed)
    gemm_pair<1, false, 0, false><<<dim3(128, 1, 1), 256, 0, stream>>>(
        keyMs_h, keyMs_l, 512, 0, tqP_h, tqP_l, 512, 0, nullptr, 0,
        KqT_h, KqT_l, nullptr, 8192, 0, 512, nullptr, nullptr, nullptr, nullptr);
    // KQ2[(t,e)][i] = (eW2_e @ KqT_e^T)[i][t]   (f32 transposed write)
    gemm_pair<6, false, 0, false><<<dim3(8, 1, 16), 256, 0, stream>>>(
        eW2s_h, eW2s_l, 512, EST, KqT_h, KqT_l, 8192, 512, nullptr, 0,
        nullptr, nullptr, KQ2, 8192, 512, 512, nullptr, nullptr, nullptr, nullptr);
    fold_misc<<<232, 256, 0, stream>>>(eb2, valM, KqT_h, KqT_l, b2V, cb);

    // ---- 3) backbone (full pair precision: feeds the score path) ----
    gemm_pair<0, true, 0, false><<<dim3(128, 4, 1), 256, 0, stream>>>(
        obs_h, obs_l, 128, 0, bW1t_h, bW1t_l, 128, 0, bb1, 0,
        t1_h, t1_l, nullptr, 512, 0, 128, nullptr, nullptr, nullptr, nullptr);
    gemm_pair<0, true, 0, false><<<dim3(128, 4, 1), 256, 0, stream>>>(
        t1_h, t1_l, 512, 0, bW2t_h, bW2t_l, 512, 0, bb2, 0,
        h2_h, h2_l, nullptr, 512, 0, 512, nullptr, nullptr, nullptr, nullptr);

    // ---- 4) pass A: one flat M=8192 x N=8192 GEMM; scores + U ----
    gemm_pair<5, true, 0, false><<<dim3(128, 64, 1), 256, 0, stream>>>(
        h2_h, h2_l, 512, 0, eW1t_h, eW1t_l, 512, 0, eb1, 0,
        U, nullptr, nullptr, 8192, 0, 512, nullptr, task, KQ2, scores);
    softmax16<<<32, 256, 0, stream>>>(scores, task, cb);

    // ---- 5) tower: twP = wb + (w .* U) @ Wv2  (1-MFMA GEMM; wb C-input,
    //         softmax scale fused in reg-staged A, single-f16 out; 512 blocks) --
    wb_init<<<8192, 256, 0, stream>>>(scores, b2V, towerAcc);
    gemm_pair<8, false, 2, true><<<dim3(128, 4, 1), 256, 0, stream>>>(
        U, nullptr, 8192, 0, Wv2_h, nullptr, 8192, 0, nullptr, 0,
        twP_h, nullptr, towerAcc, 512, 0, 8192, scores, nullptr, nullptr, nullptr);

    // ---- 6) heads: layer-1 (single x single = 1 MFMA) into Rcat, GEMV+squash --
    gemm_pair<9, true, 1, true><<<dim3(128, 4, 2), 256, 0, stream>>>(
        twP_h, nullptr, 512, 0, mW1t_h, nullptr, 512, 262144, bcat, 512,
        Rcat, nullptr, nullptr, 1024, 512, 512, nullptr, nullptr, nullptr, nullptr);
    head_kernel2<<<2048, 256, 0, stream>>>(Rcat, W2T, mb2, lb2, eps,
                                           (float*)d_out, (float*)d_out + 262144);
}

// Round 13
// 636.493 us; speedup vs baseline: 1.0513x; 1.0513x over previous
//
#include <hip/hip_runtime.h>
#include <hip/hip_bf16.h>
#include <cstdint>

// ---------------------------------------------------------------------------
// SquashedGaussianMoEActor forward, MI355X (gfx950).
// Split-f16 MFMA = fp32-quality on the score path (softmax flip-sensitivity
// forbids fewer than 3 MFMAs there); single-f16 tower path (error budget
// verified: absmax 4.0 vs threshold 14.56, R6-R12).
// R13: mixture gets split-K=2 (4 blk/CU, atomicAdd f32 into wb-seeded
// towerAcc) + XCD row-panel swizzle (A fetch 512->~140 MB). passA untouched
// (249us @ 37% MfmaUtil, XCD-swizzled).
// B=8192, OBS=128, H=D=512, E=16, T=50, A=32.
// ---------------------------------------------------------------------------

typedef _Float16 f16;
typedef _Float16 f16x4 __attribute__((ext_vector_type(4)));
typedef _Float16 f16x8 __attribute__((ext_vector_type(8)));
typedef float f32x4 __attribute__((ext_vector_type(4)));

__device__ __forceinline__ void fsplit(float x, f16& h, f16& l) {
    h = (f16)x;
    l = (f16)(x - (float)h);
}

__device__ __forceinline__ void gload16(const void* g, void* s) {
    __builtin_amdgcn_global_load_lds(
        (const __attribute__((address_space(1))) void*)g,
        (__attribute__((address_space(3))) void*)s, 16, 0, 0);
}

// --- elementwise fp32 -> f16 pair split -----------------------------------
__global__ void split_pairs(const float* __restrict__ x, f16* __restrict__ h,
                            f16* __restrict__ l, int n4) {
    int i = blockIdx.x * 256 + threadIdx.x;
    if (i >= n4) return;
    float4 v = ((const float4*)x)[i];
    float a[4] = {v.x, v.y, v.z, v.w};
    f16x4 hh, ll;
#pragma unroll
    for (int j = 0; j < 4; ++j) { f16 hj, lj; fsplit(a[j], hj, lj); hh[j] = hj; ll[j] = lj; }
    *(f16x4*)&h[(long)i * 4] = hh;
    *(f16x4*)&l[(long)i * 4] = ll;
}

// --- eW2 + keyM + obs splits in one dispatch -------------------------------
__global__ void split_pairs3(const float* __restrict__ xa, f16* __restrict__ ha,
                             f16* __restrict__ la, const float* __restrict__ xb,
                             f16* __restrict__ hb, f16* __restrict__ lb,
                             const float* __restrict__ xc, f16* __restrict__ hc,
                             f16* __restrict__ lc) {
    long i = (long)blockIdx.x * 256 + threadIdx.x;  // grid 9216 -> 2359296
    const float* x; f16* h; f16* l;
    if (i < 1048576) { x = xa; h = ha; l = la; }
    else if (i < 2097152) { i -= 1048576; x = xb; h = hb; l = lb; }
    else { i -= 2097152; x = xc; h = hc; l = lc; }
    float4 v = ((const float4*)x)[i];
    float a[4] = {v.x, v.y, v.z, v.w};
    f16x4 hh, ll;
#pragma unroll
    for (int j = 0; j < 4; ++j) { f16 hj, lj; fsplit(a[j], hj, lj); hh[j] = hj; ll[j] = lj; }
    *(f16x4*)&h[i * 4] = hh;
    *(f16x4*)&l[i * 4] = ll;
}

// --- six weight transposes in one dispatch (z = 0..35) ---------------------
// z<16: eW1_e, z<32: valM_e, 32: bW2, 33: mW1, 34: lW1, 35: bW1 (K=128).
__global__ void transpose_split6(
    const float* __restrict__ eW1, const float* __restrict__ valM,
    const float* __restrict__ bW2, const float* __restrict__ mW1,
    const float* __restrict__ lW1, const float* __restrict__ bW1,
    f16* __restrict__ eW1t_h, f16* __restrict__ eW1t_l,
    f16* __restrict__ Vt_h, f16* __restrict__ Vt_l,
    f16* __restrict__ bW2t_h, f16* __restrict__ bW2t_l,
    f16* __restrict__ mW1t_h, f16* __restrict__ mW1t_l,
    f16* __restrict__ lW1t_h, f16* __restrict__ lW1t_l,
    f16* __restrict__ bW1t_h, f16* __restrict__ bW1t_l) {
    __shared__ float t[32][33];
    const int z = blockIdx.z;
    const float* W; f16* Th; f16* Tl; int Kd = 512;
    if (z < 16) { W = eW1 + (long)z * 262144; Th = eW1t_h + (long)z * 262144; Tl = eW1t_l + (long)z * 262144; }
    else if (z < 32) { const int e = z - 16; W = valM + (long)e * 262144; Th = Vt_h + (long)e * 262144; Tl = Vt_l + (long)e * 262144; }
    else if (z == 32) { W = bW2; Th = bW2t_h; Tl = bW2t_l; }
    else if (z == 33) { W = mW1; Th = mW1t_h; Tl = mW1t_l; }
    else if (z == 34) { W = lW1; Th = lW1t_h; Tl = lW1t_l; }
    else { W = bW1; Th = bW1t_h; Tl = bW1t_l; Kd = 128; if (blockIdx.x >= 4) return; }
    const int k0 = blockIdx.x * 32, n0 = blockIdx.y * 32;
    const int tid = threadIdx.x;
    const int r = tid >> 3, c4 = (tid & 7) * 4;
    float4 v = *(const float4*)&W[(long)(k0 + r) * 512 + n0 + c4];
    t[r][c4] = v.x; t[r][c4 + 1] = v.y; t[r][c4 + 2] = v.z; t[r][c4 + 3] = v.w;
    __syncthreads();
    f16x4 hh, ll;
#pragma unroll
    for (int j = 0; j < 4; ++j) { f16 hj, lj; fsplit(t[c4 + j][r], hj, lj); hh[j] = hj; ll[j] = lj; }
    const long ob = (long)(n0 + r) * Kd + k0 + c4;
    *(f16x4*)&Th[ob] = hh;
    *(f16x4*)&Tl[ob] = ll;
}

// --- W2T[half][col][k] + bcat = [mb1;lb1] in one dispatch ------------------
__global__ void build_w2t_bcat(const float* __restrict__ mW2, const float* __restrict__ lW2,
                               const float* __restrict__ mb1, const float* __restrict__ lb1,
                               float* __restrict__ W2T, float* __restrict__ bcat) {
    const int i = blockIdx.x * 256 + threadIdx.x;  // grid 132 -> 33792
    if (i < 32768) {
        const int half = i >> 14, col = (i >> 9) & 31, k = i & 511;
        const float* src = half ? lW2 : mW2;
        W2T[i] = src[k * 32 + col];
    } else {
        const int j = i - 32768;
        if (j < 1024) bcat[j] = (j < 512) ? mb1[j] : lb1[j - 512];
    }
}

// --- b2V fold + cb-from-Kq in one dispatch ---------------------------------
__global__ void fold_misc(const float* __restrict__ eb2, const float* __restrict__ valM,
                          const f16* __restrict__ KqT_h, const f16* __restrict__ KqT_l,
                          float* __restrict__ b2V, float* __restrict__ cb) {
    if (blockIdx.x < 32) {
        // b2V[e*512+j] = sum_k eb2[e,k] * valM[e][k][j]
        const int gid = blockIdx.x * 256 + threadIdx.x;  // 8192
        const int e = gid >> 9, j = gid & 511;
        const float* Me = valM + (long)e * 262144;
        const float* be = eb2 + e * 512;
        float s = 0.f;
        for (int k = 0; k < 512; ++k) s += be[k] * Me[(long)k * 512 + j];
        b2V[gid] = s;
    } else {
        // cb[t][e] = sum_k eb2[e,k] * Kq[e,k,t]
        const int gw = ((blockIdx.x - 32) * 256 + threadIdx.x) >> 6;  // 0..799
        const int l = threadIdx.x & 63;
        const int t = gw >> 4, e = gw & 15;
        const long base = (long)t * 8192 + e * 512 + l * 8;
        f16x8 hh = *(const f16x8*)&KqT_h[base];
        f16x8 ll = *(const f16x8*)&KqT_l[base];
        const float* bb = eb2 + e * 512 + l * 8;
        float s = 0.f;
#pragma unroll
        for (int j = 0; j < 8; ++j) s += ((float)hh[j] + (float)ll[j]) * bb[j];
#pragma unroll
        for (int d = 1; d < 64; d <<= 1) s += __shfl_xor(s, d);
        if (l == 0) cb[t * 16 + e] = s;
    }
}

// --- towerAcc f32 -> twP single f16 ---------------------------------------
__global__ void tw_convert(const float* __restrict__ acc, f16* __restrict__ out) {
    const int i = blockIdx.x * 256 + threadIdx.x;  // 1048576 float4 groups
    float4 v = ((const float4*)acc)[i];
    f16x4 o; o[0] = (f16)v.x; o[1] = (f16)v.y; o[2] = (f16)v.z; o[3] = (f16)v.w;
    *(f16x4*)&out[(long)i * 4] = o;
}

// --- split-f16 GEMM: C = act(A @ B^T_stored + bias) ------------------------
// Tile 64x128, BK=64, 4 waves each owning 32x64 (2x4 frags of 16x16x32).
// Staging via global_load_lds (linear LDS dest, pre-swizzled global source;
// read side applies the same chunk^=row&7 involution). Single-buffered,
// 3-6 blocks/CU -- inter-block overlap hides barrier drains (m114).
// OUTM: 0 pair write, 1 pair write transposed, 2 f32 write, 3 f32 accum,
//       5 score mode (flat expert=col0>>9; XCD y-chunk swizzle; row-dot KQ2
//         -> atomicAdd) + write t1 single-f16 to Ch (U), 6 f32 transposed,
//       7 single-f16 write transposed, 9 single-f16 plain write,
//       10 f32 atomicAdd accumulate (split-K mixture; XCD row-panel swizzle;
//          z = K-partition: Ah/Bh offset by z*zs, wscale by z*8).
// AMODE: 0 = A pair (gload, 3rd MFMA), 1 = A single (gload),
//        2 = A single reg-staged with fused per-(row, k-block) wscale.
// BSINGLE: B single plane (skips the AhBl MFMA).
template <int OUTM, bool RELU, int AMODE, bool BSINGLE>
__global__ __launch_bounds__(256, (AMODE == 0 && !BSINGLE) ? 3 : (AMODE == 0 ? 4 : 6))
void gemm_pair(
    const f16* __restrict__ Ah, const f16* __restrict__ Al, int lda, long zsA,
    const f16* __restrict__ Bh, const f16* __restrict__ Bl, int ldb, long zsB,
    const float* __restrict__ bias, long zsBias,
    f16* __restrict__ Ch, f16* __restrict__ Cl, float* __restrict__ Cf,
    int ldc, long zsC, int K,
    const float* __restrict__ wscale,
    const int* __restrict__ task, const float* __restrict__ KQ2,
    float* __restrict__ scores) {
    __shared__ f16 As[AMODE == 0 ? 2 : 1][64][64];
    __shared__ f16 Bs[BSINGLE ? 1 : 2][128][64];
    const int z = blockIdx.z;
    Ah += (long)z * zsA;
    if constexpr (AMODE == 0) Al += (long)z * zsA;
    Bh += (long)z * zsB;
    if constexpr (!BSINGLE) Bl += (long)z * zsB;
    if (bias) bias += (long)z * zsBias;
    if (OUTM <= 1) { Ch += (long)z * zsC; Cl += (long)z * zsC; }
    if (OUTM == 7 || OUTM == 9) { Ch += (long)z * zsC; }
    if (OUTM == 2 || OUTM == 3 || OUTM == 6) { Cf += (long)z * zsC; }
    if constexpr (OUTM == 10) { if (wscale) wscale += (long)z * 8; }
    const int tid = threadIdx.x;
    const int l = tid & 63;
    const int w = tid >> 6;
    int bx = blockIdx.x, by = blockIdx.y;
    if constexpr (OUTM == 5) {
        // XCD y-chunk swizzle (R10-verified): grid (128,64); each XCD owns 8
        // contiguous col-tiles -> its B pair working set stays L2-resident.
        const int id = by * gridDim.x + bx;
        const int xcd = id & 7, r = id >> 3;
        by = (xcd << 3) | (r & 7);
        bx = r >> 3;
    }
    if constexpr (OUTM == 10) {
        // XCD row-panel swizzle: grid (128,4); 4 consecutive same-XCD blocks
        // share one 1MB A row-panel -> L2-resident reuse (A fetch /4).
        const int fid = by * gridDim.x + bx;
        const int xcd = fid & 7, k = fid >> 3;   // k in 0..63
        bx = xcd * 16 + (k >> 2);
        by = k & 3;
    }
    const int row0 = bx * 64;
    const int col0 = by * 128;
    const int wr = (w >> 1) * 32;
    const int wc = (w & 1) * 64;
    const int grow = l >> 3;           // row within 8-row group
    const int gch = (l & 7) ^ grow;    // pre-swizzled k-chunk for gload_lds

    f32x4 acc[2][4];
#pragma unroll
    for (int mi = 0; mi < 2; ++mi)
#pragma unroll
        for (int ni = 0; ni < 4; ++ni)
#pragma unroll
            for (int j = 0; j < 4; ++j) acc[mi][ni][j] = 0.f;

    // AMODE==2: reg-staged A with fused per-(row, k-block) scale
    uint4 areg0, areg1; float ascl0, ascl1;
    auto ldA = [&](int k0) {
        const int r0 = w * 16 + grow, r1 = r0 + 8;
        const int scl = l & 7;
        areg0 = *(const uint4*)&Ah[(long)(row0 + r0) * lda + k0 + scl * 8];
        areg1 = *(const uint4*)&Ah[(long)(row0 + r1) * lda + k0 + scl * 8];
        const int e = k0 >> 9;
        ascl0 = wscale[(long)(row0 + r0) * 16 + e];
        ascl1 = wscale[(long)(row0 + r1) * 16 + e];
    };
    auto wrA = [&]() {
        const int scl = l & 7;
#pragma unroll
        for (int h = 0; h < 2; ++h) {
            const int r = w * 16 + grow + h * 8;
            const float s = h ? ascl1 : ascl0;
            f16x8 v = h ? *(f16x8*)&areg1 : *(f16x8*)&areg0;
#pragma unroll
            for (int j = 0; j < 8; ++j) v[j] = (f16)((float)v[j] * s);
            *(uint4*)&As[0][r][(scl ^ (r & 7)) * 8] = *(uint4*)&v;
        }
    };

    if constexpr (AMODE == 2) ldA(0);
    for (int k0 = 0; k0 < K; k0 += 64) {
        __syncthreads();
        if constexpr (AMODE == 2) {
            wrA();
            if (k0 + 64 < K) ldA(k0 + 64);  // next loads issued early (hidden under compute)
        } else {
            // A: wave w stages rows [w*16, w*16+16)
            const long ga = (long)(row0 + w * 16 + grow) * lda + k0 + gch * 8;
            gload16(Ah + ga, &As[0][w * 16][0]);
            gload16(Ah + ga + (long)8 * lda, &As[0][w * 16 + 8][0]);
            if constexpr (AMODE == 0) {
                gload16(Al + ga, &As[1][w * 16][0]);
                gload16(Al + ga + (long)8 * lda, &As[1][w * 16 + 8][0]);
            }
        }
        {
            // B: wave w stages rows [w*32, w*32+32)
            const long gb = (long)(col0 + w * 32 + grow) * ldb + k0 + gch * 8;
            gload16(Bh + gb, &Bs[0][w * 32][0]);
            gload16(Bh + gb + (long)8 * ldb, &Bs[0][w * 32 + 8][0]);
            gload16(Bh + gb + (long)16 * ldb, &Bs[0][w * 32 + 16][0]);
            gload16(Bh + gb + (long)24 * ldb, &Bs[0][w * 32 + 24][0]);
            if constexpr (!BSINGLE) {
                gload16(Bl + gb, &Bs[1][w * 32][0]);
                gload16(Bl + gb + (long)8 * ldb, &Bs[1][w * 32 + 8][0]);
                gload16(Bl + gb + (long)16 * ldb, &Bs[1][w * 32 + 16][0]);
                gload16(Bl + gb + (long)24 * ldb, &Bs[1][w * 32 + 24][0]);
            }
        }
        __syncthreads();
        const int r16 = l & 15, kg = l >> 4;
#pragma unroll
        for (int ks = 0; ks < 2; ++ks) {
            f16x8 a_h[2], a_l[2], b_h[4], b_l[4];
#pragma unroll
            for (int mi = 0; mi < 2; ++mi) {
                const int r = wr + mi * 16 + r16;
                const int off = ((ks * 4 + kg) ^ (r & 7)) * 8;
                a_h[mi] = *(const f16x8*)&As[0][r][off];
                if constexpr (AMODE == 0) a_l[mi] = *(const f16x8*)&As[1][r][off];
            }
#pragma unroll
            for (int ni = 0; ni < 4; ++ni) {
                const int c = wc + ni * 16 + r16;
                const int off = ((ks * 4 + kg) ^ (c & 7)) * 8;
                b_h[ni] = *(const f16x8*)&Bs[0][c][off];
                if constexpr (!BSINGLE) b_l[ni] = *(const f16x8*)&Bs[1][c][off];
            }
#pragma unroll
            for (int mi = 0; mi < 2; ++mi)
#pragma unroll
                for (int ni = 0; ni < 4; ++ni) {
                    acc[mi][ni] = __builtin_amdgcn_mfma_f32_16x16x32_f16(a_h[mi], b_h[ni], acc[mi][ni], 0, 0, 0);
                    if constexpr (!BSINGLE)
                        acc[mi][ni] = __builtin_amdgcn_mfma_f32_16x16x32_f16(a_h[mi], b_l[ni], acc[mi][ni], 0, 0, 0);
                    if constexpr (AMODE == 0)
                        acc[mi][ni] = __builtin_amdgcn_mfma_f32_16x16x32_f16(a_l[mi], b_h[ni], acc[mi][ni], 0, 0, 0);
                }
        }
    }
    // epilogue. C layout (m89-verified): col = lane&15, row = (lane>>4)*4 + reg.
    const int lane15 = l & 15;
    const int rsub = (l >> 4) * 4;
    if (OUTM == 5) {
        const int expert = col0 >> 9;
        float bv[4];
#pragma unroll
        for (int ni = 0; ni < 4; ++ni)
            bv[ni] = bias ? bias[col0 + wc + ni * 16 + lane15] : 0.f;
#pragma unroll
        for (int mi = 0; mi < 2; ++mi)
#pragma unroll
            for (int j = 0; j < 4; ++j) {
                const int rowg = row0 + wr + mi * 16 + rsub + j;
                const int t = task[rowg];
                const float* kqr = KQ2 + ((long)t * 16 + expert) * 512;
                float part = 0.f;
#pragma unroll
                for (int ni = 0; ni < 4; ++ni) {
                    const int colg = col0 + wc + ni * 16 + lane15;
                    float v = acc[mi][ni][j] + bv[ni];
                    if (RELU) v = fmaxf(v, 0.f);
                    Ch[(long)rowg * ldc + colg] = (f16)v;
                    part += v * kqr[colg & 511];
                }
#pragma unroll
                for (int d = 1; d < 16; d <<= 1) part += __shfl_xor(part, d);
                if (lane15 == 0) atomicAdd(&scores[rowg * 16 + expert], part);
            }
    } else {
#pragma unroll
        for (int mi = 0; mi < 2; ++mi)
#pragma unroll
            for (int ni = 0; ni < 4; ++ni) {
                const int colg = col0 + wc + ni * 16 + lane15;
                const float bv = bias ? bias[colg] : 0.f;
#pragma unroll
                for (int j = 0; j < 4; ++j) {
                    const int rowg = row0 + wr + mi * 16 + rsub + j;
                    float v = acc[mi][ni][j] + bv;
                    if (RELU) v = fmaxf(v, 0.f);
                    if (OUTM == 0) {
                        f16 hh, ll; fsplit(v, hh, ll);
                        const long idx = (long)rowg * ldc + colg;
                        Ch[idx] = hh; Cl[idx] = ll;
                    } else if (OUTM == 1) {
                        f16 hh, ll; fsplit(v, hh, ll);
                        const long idx = (long)colg * ldc + rowg;
                        Ch[idx] = hh; Cl[idx] = ll;
                    } else if (OUTM == 2) {
                        Cf[(long)rowg * ldc + colg] = v;
                    } else if (OUTM == 3) {
                        Cf[(long)rowg * ldc + colg] += v;
                    } else if (OUTM == 6) {
                        Cf[(long)colg * ldc + rowg] = v;
                    } else if (OUTM == 7) {
                        Ch[(long)colg * ldc + rowg] = (f16)v;
                    } else if (OUTM == 9) {
                        Ch[(long)rowg * ldc + colg] = (f16)v;
                    } else if (OUTM == 10) {
                        atomicAdd(&Cf[(long)rowg * ldc + colg], v);
                    }
                }
            }
    }
}

// --- softmax over E=16 per row; adds cb[task[b]] (scores pre-zeroed) -------
__global__ void softmax16(float* __restrict__ sc, const int* __restrict__ task,
                          const float* __restrict__ cb) {
    const int b = blockIdx.x * 256 + threadIdx.x;  // 8192
    const float* cbr = cb + task[b] * 16;
    float v[16];
    const float4* pp = (const float4*)&sc[b * 16];
    const float4* cp = (const float4*)cbr;
#pragma unroll
    for (int qq = 0; qq < 4; ++qq) {
        float4 t = pp[qq];
        float4 c = cp[qq];
        v[qq * 4] = t.x + c.x; v[qq * 4 + 1] = t.y + c.y;
        v[qq * 4 + 2] = t.z + c.z; v[qq * 4 + 3] = t.w + c.w;
    }
    float m = v[0];
#pragma unroll
    for (int e = 1; e < 16; ++e) m = fmaxf(m, v[e]);
    float ssum = 0.f;
#pragma unroll
    for (int e = 0; e < 16; ++e) { v[e] = expf(v[e] - m); ssum += v[e]; }
    const float inv = 1.f / ssum;
    float4* o = (float4*)&sc[b * 16];
#pragma unroll
    for (int qq = 0; qq < 4; ++qq) {
        float4 t;
        t.x = v[qq * 4] * inv; t.y = v[qq * 4 + 1] * inv;
        t.z = v[qq * 4 + 2] * inv; t.w = v[qq * 4 + 3] * inv;
        o[qq] = t;
    }
}

// --- towerAcc[b][j] = sum_e w[b][e] * b2V[e][j] ----------------------------
__global__ void wb_init(const float* __restrict__ w, const float* __restrict__ b2V,
                        float* __restrict__ towerAcc) {
    const int b = blockIdx.x;
    const int tid = threadIdx.x;
    float wv[16];
#pragma unroll
    for (int e = 0; e < 16; ++e) wv[e] = w[b * 16 + e];
#pragma unroll
    for (int rep = 0; rep < 2; ++rep) {
        const int j = rep * 256 + tid;
        float s = 0.f;
#pragma unroll
        for (int e = 0; e < 16; ++e) s += wv[e] * b2V[e * 512 + j];
        towerAcc[(long)b * 512 + j] = s;
    }
}

// --- final heads: GEMV vs W2T (float4 streams), squash, logp ---------------
// Rcat: [8192][1024] single f16; cols 0..511 = mu path, 512..1023 = ls path.
__global__ void head_kernel2(
    const f16* __restrict__ Rh,
    const float* __restrict__ W2T,   // [2][32][512]
    const float* __restrict__ mb2, const float* __restrict__ lb2,
    const float* __restrict__ eps, float* __restrict__ pi, float* __restrict__ logp) {
    __shared__ float src[4][1032];
    const int tid = threadIdx.x, l = tid & 63, w = tid >> 6;
    const int b = blockIdx.x * 4 + w;  // one wave per row
    const long rb = (long)b * 1024;
    {
        f16x8 h0 = *(const f16x8*)&Rh[rb + l * 8];
        f16x8 h1 = *(const f16x8*)&Rh[rb + 512 + l * 8];
#pragma unroll
        for (int j = 0; j < 8; ++j) {
            src[w][l * 8 + j] = (float)h0[j];
            src[w][512 + l * 8 + j] = (float)h1[j];
        }
    }
    __syncthreads();
    const int col = l & 31;
    const int half = l >> 5;  // 0 = mu, 1 = log_std
    const float4* wp = (const float4*)(W2T + ((long)(half * 32 + col)) * 512);
    const float4* sp = (const float4*)(&src[w][half * 512]);
    float a0 = 0.f, a1 = 0.f, a2 = 0.f, a3 = 0.f;
#pragma unroll 8
    for (int k4 = 0; k4 < 128; ++k4) {
        const float4 wv = wp[k4];
        const float4 sv = sp[k4];
        a0 = fmaf(wv.x, sv.x, a0);
        a1 = fmaf(wv.y, sv.y, a1);
        a2 = fmaf(wv.z, sv.z, a2);
        a3 = fmaf(wv.w, sv.w, a3);
    }
    const float* b2 = half ? lb2 : mb2;
    float s = b2[col] + ((a0 + a1) + (a2 + a3));
    const float other = __shfl_xor(s, 32);  // swap mu <-> log_std halves
    if (half == 0) {
        const float mu = s;
        float ls = fminf(fmaxf(other, -20.f), 2.f);
        const float e = eps[(long)b * 32 + col];
        const float a = mu + expf(ls) * e;
        float lt = -0.5f * e * e - ls - 0.91893853320467274f;  // -0.5*log(2*pi)
        const float x = -2.f * a;
        const float sp2 = fmaxf(x, 0.f) + log1pf(expf(-fabsf(x)));
        lt -= 2.f * (0.69314718055994531f - a - sp2);
        pi[(long)b * 32 + col] = tanhf(a);
        float r = lt;
#pragma unroll
        for (int d = 1; d < 32; d <<= 1) r += __shfl_xor(r, d);
        if (col == 0) logp[b] = r;
    }
}

// ---------------------------------------------------------------------------
extern "C" void kernel_launch(void* const* d_in, const int* in_sizes, int n_in,
                              void* d_out, int out_size, void* d_ws, size_t ws_size,
                              hipStream_t stream) {
    const float* obs = (const float*)d_in[0];
    const int* task = (const int*)d_in[1];
    const float* eps = (const float*)d_in[2];
    const float* bW1 = (const float*)d_in[3];
    const float* bb1 = (const float*)d_in[4];
    const float* bW2 = (const float*)d_in[5];
    const float* bb2 = (const float*)d_in[6];
    const float* eW1 = (const float*)d_in[7];
    const float* eb1 = (const float*)d_in[8];
    const float* eW2 = (const float*)d_in[9];
    const float* eb2 = (const float*)d_in[10];
    const float* keyM = (const float*)d_in[11];
    const float* valM = (const float*)d_in[12];
    const float* tq = (const float*)d_in[13];
    const float* mW1 = (const float*)d_in[14];
    const float* mb1 = (const float*)d_in[15];
    const float* mW2 = (const float*)d_in[16];
    const float* mb2 = (const float*)d_in[17];
    const float* lW1 = (const float*)d_in[18];
    const float* lb1 = (const float*)d_in[19];
    const float* lW2 = (const float*)d_in[20];
    const float* lb2 = (const float*)d_in[21];
    (void)in_sizes; (void)n_in; (void)out_size; (void)ws_size;

    // ---- workspace map (base 122 MB + 128 MB U; ws >= 251 MB verified R4) --
    const size_t MB = 1u << 20, KB = 1u << 10;
    char* base = (char*)d_ws;
    f16* eW1t_h = (f16*)(base + 0 * MB);   f16* eW1t_l = (f16*)(base + 8 * MB);
    f16* Wv2_h  = (f16*)(base + 16 * MB);  // [j2][(e,i)] single f16
    f16* eW2s_h = (f16*)(base + 32 * MB);  f16* eW2s_l = (f16*)(base + 40 * MB);
    f16* h2_h   = (f16*)(base + 32 * MB);  f16* h2_l   = (f16*)(base + 40 * MB);  // after folds
    f16* t1_h   = (f16*)(base + 48 * MB);  f16* t1_l   = (f16*)(base + 56 * MB);
    f16* Rcat   = (f16*)(base + 48 * MB);                                         // heads (t1 dead), 16 MB single
    f16* Vt_h   = (f16*)(base + 64 * MB);  f16* Vt_l   = (f16*)(base + 72 * MB);
    // 80-112 MB region, phase 1 (KQ path): keyM pairs, KqT, tqP, KQ2
    f16* keyMs_h = (f16*)(base + 80 * MB); f16* keyMs_l = (f16*)(base + 88 * MB);
    f16* KqT_h   = (f16*)(base + 96 * MB); f16* KqT_l   = (f16*)(base + 98 * MB); // [128][8192]
    f16* tqP_h   = (f16*)(base + 100 * MB); f16* tqP_l  = (f16*)(base + 100 * MB + 128 * KB); // [128][512]
    float* KQ2   = (float*)(base + 104 * MB);                                     // [128][16][512] f32
    // 80-112 MB region, phase 2 (tower/heads): towerAcc (wb), twP (single)
    float* towerAcc = (float*)(base + 80 * MB);                                   // 16 MB
    f16* twP_h  = (f16*)(base + 96 * MB);
    f16* obs_h  = (f16*)(base + 112 * MB); f16* obs_l  = (f16*)(base + 114 * MB);
    char* q = base + 116 * MB;
    f16* bW1t_h = (f16*)q; q += 128 * KB;  f16* bW1t_l = (f16*)q; q += 128 * KB;
    f16* bW2t_h = (f16*)q; q += 512 * KB;  f16* bW2t_l = (f16*)q; q += 512 * KB;
    // order m_h, l_h, m_l, l_l so the z=2 head GEMM can stride (zsB = 262144)
    f16* mW1t_h = (f16*)q; q += 512 * KB;
    f16* lW1t_h = (f16*)q; q += 512 * KB;
    f16* mW1t_l = (f16*)q; q += 512 * KB;
    f16* lW1t_l = (f16*)q; q += 512 * KB;
    float* scores = (float*)q; q += 512 * KB;    // 8192*16 f32 (becomes w)
    float* b2V    = (float*)q; q += 32 * KB;
    float* cb     = (float*)q; q += 16 * KB;
    float* W2T    = (float*)q; q += 128 * KB;    // [2][32][512]
    float* bcat   = (float*)q; q += 16 * KB;     // [2][512]
    f16* U = (f16*)(base + 122 * MB);            // [8192][8192] single f16

    const long EST = 262144;  // per-expert 512x512 stride

    // ---- 1) splits / transposes ----
    hipMemsetAsync(tqP_h, 0, 256 * KB, stream);   // tqP_h and tqP_l contiguous
    hipMemsetAsync(scores, 0, 512 * KB, stream);  // passA atomicAdd target
    split_pairs3<<<9216, 256, 0, stream>>>(eW2, eW2s_h, eW2s_l, keyM, keyMs_h, keyMs_l,
                                           obs, obs_h, obs_l);
    split_pairs<<<25, 256, 0, stream>>>(tq, tqP_h, tqP_l, 6400);
    transpose_split6<<<dim3(16, 16, 36), 256, 0, stream>>>(
        eW1, valM, bW2, mW1, lW1, bW1, eW1t_h, eW1t_l, Vt_h, Vt_l,
        bW2t_h, bW2t_l, mW1t_h, mW1t_l, lW1t_h, lW1t_l, bW1t_h, bW1t_l);
    build_w2t_bcat<<<132, 256, 0, stream>>>(mW2, lW2, mb1, lb1, W2T, bcat);

    // ---- 2) attention folds ----
    // Wv2[j2][(e,i)] = (eW2@V)[i][j2]  (single-f16 out -> 2-MFMA: A pair x B single)
    gemm_pair<7, false, 0, true><<<dim3(8, 4, 16), 256, 0, stream>>>(
        eW2s_h, eW2s_l, 512, EST, Vt_h, nullptr, 512, EST, nullptr, 0,
        Wv2_h, nullptr, nullptr, 8192, 512, 512, nullptr, nullptr, nullptr, nullptr);
    // KqT[t][(e,k)] = (keyM @ tq^T)[(e,k)][t]   (N=128 padded, pair transposed)
    gemm_pair<1, false, 0, false><<<dim3(128, 1, 1), 256, 0, stream>>>(
        keyMs_h, keyMs_l, 512, 0, tqP_h, tqP_l, 512, 0, nullptr, 0,
        KqT_h, KqT_l, nullptr, 8192, 0, 512, nullptr, nullptr, nullptr, nullptr);
    // KQ2[(t,e)][i] = (eW2_e @ KqT_e^T)[i][t]   (f32 transposed write)
    gemm_pair<6, false, 0, false><<<dim3(8, 1, 16), 256, 0, stream>>>(
        eW2s_h, eW2s_l, 512, EST, KqT_h, KqT_l, 8192, 512, nullptr, 0,
        nullptr, nullptr, KQ2, 8192, 512, 512, nullptr, nullptr, nullptr, nullptr);
    fold_misc<<<232, 256, 0, stream>>>(eb2, valM, KqT_h, KqT_l, b2V, cb);

    // ---- 3) backbone (full pair precision: feeds the score path) ----
    gemm_pair<0, true, 0, false><<<dim3(128, 4, 1), 256, 0, stream>>>(
        obs_h, obs_l, 128, 0, bW1t_h, bW1t_l, 128, 0, bb1, 0,
        t1_h, t1_l, nullptr, 512, 0, 128, nullptr, nullptr, nullptr, nullptr);
    gemm_pair<0, true, 0, false><<<dim3(128, 4, 1), 256, 0, stream>>>(
        t1_h, t1_l, 512, 0, bW2t_h, bW2t_l, 512, 0, bb2, 0,
        h2_h, h2_l, nullptr, 512, 0, 512, nullptr, nullptr, nullptr, nullptr);

    // ---- 4) pass A: one flat M=8192 x N=8192 GEMM; scores + U ----
    gemm_pair<5, true, 0, false><<<dim3(128, 64, 1), 256, 0, stream>>>(
        h2_h, h2_l, 512, 0, eW1t_h, eW1t_l, 512, 0, eb1, 0,
        U, nullptr, nullptr, 8192, 0, 512, nullptr, task, KQ2, scores);
    softmax16<<<32, 256, 0, stream>>>(scores, task, cb);

    // ---- 5) tower: towerAcc = wb + (w .* U) @ Wv2  (split-K=2, 1-MFMA,
    //         XCD row-panel swizzle, f32 atomicAdd), then f16 convert ----
    wb_init<<<8192, 256, 0, stream>>>(scores, b2V, towerAcc);
    gemm_pair<10, false, 2, true><<<dim3(128, 4, 2), 256, 0, stream>>>(
        U, nullptr, 8192, 4096, Wv2_h, nullptr, 8192, 4096, nullptr, 0,
        nullptr, nullptr, towerAcc, 512, 0, 4096, scores, nullptr, nullptr, nullptr);
    tw_convert<<<4096, 256, 0, stream>>>(towerAcc, twP_h);

    // ---- 6) heads: layer-1 (single x single = 1 MFMA) into Rcat, GEMV+squash --
    gemm_pair<9, true, 1, true><<<dim3(128, 4, 2), 256, 0, stream>>>(
        twP_h, nullptr, 512, 0, mW1t_h, nullptr, 512, 262144, bcat, 512,
        Rcat, nullptr, nullptr, 1024, 512, 512, nullptr, nullptr, nullptr, nullptr);
    head_kernel2<<<2048, 256, 0, stream>>>(Rcat, W2T, mb2, lb2, eps,
                                           (float*)d_out, (float*)d_out + 262144);
}

// Round 14
// 631.185 us; speedup vs baseline: 1.0601x; 1.0084x over previous
//
#include <hip/hip_runtime.h>
#include <hip/hip_bf16.h>
#include <cstdint>

// ---------------------------------------------------------------------------
// SquashedGaussianMoEActor forward, MI355X (gfx950).
// Split-f16 MFMA = fp32-quality on the score path (softmax flip-sensitivity
// forbids fewer than 3 MFMAs there); single-f16 tower path (error budget
// verified: absmax 4.0 vs threshold 14.56, R6-R13).
// R14: atomic-free split-K mixture (per-partition output buffers, summed in
// tw_convert), tq split folded into the big split kernel. passA untouched
// (249us @ 37% MfmaUtil, XCD-swizzled -- proven structural floor).
// B=8192, OBS=128, H=D=512, E=16, T=50, A=32.
// ---------------------------------------------------------------------------

typedef _Float16 f16;
typedef _Float16 f16x4 __attribute__((ext_vector_type(4)));
typedef _Float16 f16x8 __attribute__((ext_vector_type(8)));
typedef float f32x4 __attribute__((ext_vector_type(4)));

__device__ __forceinline__ void fsplit(float x, f16& h, f16& l) {
    h = (f16)x;
    l = (f16)(x - (float)h);
}

__device__ __forceinline__ void gload16(const void* g, void* s) {
    __builtin_amdgcn_global_load_lds(
        (const __attribute__((address_space(1))) void*)g,
        (__attribute__((address_space(3))) void*)s, 16, 0, 0);
}

// --- eW2 + keyM + obs + tq splits in one dispatch --------------------------
// grid 9241 x 256 = 2365696 = 1048576 + 1048576 + 262144 + 6400 (exact).
__global__ void split_pairs4(const float* __restrict__ xa, f16* __restrict__ ha,
                             f16* __restrict__ la, const float* __restrict__ xb,
                             f16* __restrict__ hb, f16* __restrict__ lb,
                             const float* __restrict__ xc, f16* __restrict__ hc,
                             f16* __restrict__ lc, const float* __restrict__ xd,
                             f16* __restrict__ hd, f16* __restrict__ ld) {
    long i = (long)blockIdx.x * 256 + threadIdx.x;
    const float* x; f16* h; f16* l;
    if (i < 1048576) { x = xa; h = ha; l = la; }
    else if (i < 2097152) { i -= 1048576; x = xb; h = hb; l = lb; }
    else if (i < 2359296) { i -= 2097152; x = xc; h = hc; l = lc; }
    else { i -= 2359296; x = xd; h = hd; l = ld; }
    float4 v = ((const float4*)x)[i];
    float a[4] = {v.x, v.y, v.z, v.w};
    f16x4 hh, ll;
#pragma unroll
    for (int j = 0; j < 4; ++j) { f16 hj, lj; fsplit(a[j], hj, lj); hh[j] = hj; ll[j] = lj; }
    *(f16x4*)&h[i * 4] = hh;
    *(f16x4*)&l[i * 4] = ll;
}

// --- six weight transposes in one dispatch (z = 0..35) ---------------------
// z<16: eW1_e, z<32: valM_e, 32: bW2, 33: mW1, 34: lW1, 35: bW1 (K=128).
__global__ void transpose_split6(
    const float* __restrict__ eW1, const float* __restrict__ valM,
    const float* __restrict__ bW2, const float* __restrict__ mW1,
    const float* __restrict__ lW1, const float* __restrict__ bW1,
    f16* __restrict__ eW1t_h, f16* __restrict__ eW1t_l,
    f16* __restrict__ Vt_h, f16* __restrict__ Vt_l,
    f16* __restrict__ bW2t_h, f16* __restrict__ bW2t_l,
    f16* __restrict__ mW1t_h, f16* __restrict__ mW1t_l,
    f16* __restrict__ lW1t_h, f16* __restrict__ lW1t_l,
    f16* __restrict__ bW1t_h, f16* __restrict__ bW1t_l) {
    __shared__ float t[32][33];
    const int z = blockIdx.z;
    const float* W; f16* Th; f16* Tl; int Kd = 512;
    if (z < 16) { W = eW1 + (long)z * 262144; Th = eW1t_h + (long)z * 262144; Tl = eW1t_l + (long)z * 262144; }
    else if (z < 32) { const int e = z - 16; W = valM + (long)e * 262144; Th = Vt_h + (long)e * 262144; Tl = Vt_l + (long)e * 262144; }
    else if (z == 32) { W = bW2; Th = bW2t_h; Tl = bW2t_l; }
    else if (z == 33) { W = mW1; Th = mW1t_h; Tl = mW1t_l; }
    else if (z == 34) { W = lW1; Th = lW1t_h; Tl = lW1t_l; }
    else { W = bW1; Th = bW1t_h; Tl = bW1t_l; Kd = 128; if (blockIdx.x >= 4) return; }
    const int k0 = blockIdx.x * 32, n0 = blockIdx.y * 32;
    const int tid = threadIdx.x;
    const int r = tid >> 3, c4 = (tid & 7) * 4;
    float4 v = *(const float4*)&W[(long)(k0 + r) * 512 + n0 + c4];
    t[r][c4] = v.x; t[r][c4 + 1] = v.y; t[r][c4 + 2] = v.z; t[r][c4 + 3] = v.w;
    __syncthreads();
    f16x4 hh, ll;
#pragma unroll
    for (int j = 0; j < 4; ++j) { f16 hj, lj; fsplit(t[c4 + j][r], hj, lj); hh[j] = hj; ll[j] = lj; }
    const long ob = (long)(n0 + r) * Kd + k0 + c4;
    *(f16x4*)&Th[ob] = hh;
    *(f16x4*)&Tl[ob] = ll;
}

// --- W2T[half][col][k] + bcat = [mb1;lb1] in one dispatch ------------------
__global__ void build_w2t_bcat(const float* __restrict__ mW2, const float* __restrict__ lW2,
                               const float* __restrict__ mb1, const float* __restrict__ lb1,
                               float* __restrict__ W2T, float* __restrict__ bcat) {
    const int i = blockIdx.x * 256 + threadIdx.x;  // grid 132 -> 33792
    if (i < 32768) {
        const int half = i >> 14, col = (i >> 9) & 31, k = i & 511;
        const float* src = half ? lW2 : mW2;
        W2T[i] = src[k * 32 + col];
    } else {
        const int j = i - 32768;
        if (j < 1024) bcat[j] = (j < 512) ? mb1[j] : lb1[j - 512];
    }
}

// --- b2V fold + cb-from-Kq in one dispatch ---------------------------------
__global__ void fold_misc(const float* __restrict__ eb2, const float* __restrict__ valM,
                          const f16* __restrict__ KqT_h, const f16* __restrict__ KqT_l,
                          float* __restrict__ b2V, float* __restrict__ cb) {
    if (blockIdx.x < 32) {
        const int gid = blockIdx.x * 256 + threadIdx.x;  // 8192
        const int e = gid >> 9, j = gid & 511;
        const float* Me = valM + (long)e * 262144;
        const float* be = eb2 + e * 512;
        float s = 0.f;
        for (int k = 0; k < 512; ++k) s += be[k] * Me[(long)k * 512 + j];
        b2V[gid] = s;
    } else {
        const int gw = ((blockIdx.x - 32) * 256 + threadIdx.x) >> 6;  // 0..799
        const int l = threadIdx.x & 63;
        const int t = gw >> 4, e = gw & 15;
        const long base = (long)t * 8192 + e * 512 + l * 8;
        f16x8 hh = *(const f16x8*)&KqT_h[base];
        f16x8 ll = *(const f16x8*)&KqT_l[base];
        const float* bb = eb2 + e * 512 + l * 8;
        float s = 0.f;
#pragma unroll
        for (int j = 0; j < 8; ++j) s += ((float)hh[j] + (float)ll[j]) * bb[j];
#pragma unroll
        for (int d = 1; d < 64; d <<= 1) s += __shfl_xor(s, d);
        if (l == 0) cb[t * 16 + e] = s;
    }
}

// --- twP = (f16)(acc1 + acc2)  (split-K partial sum + f16 convert) ---------
__global__ void tw_convert(const float* __restrict__ acc1, const float* __restrict__ acc2,
                           f16* __restrict__ out) {
    const int i = blockIdx.x * 256 + threadIdx.x;  // 1048576 float4 groups
    float4 a = ((const float4*)acc1)[i];
    float4 b = ((const float4*)acc2)[i];
    f16x4 o;
    o[0] = (f16)(a.x + b.x); o[1] = (f16)(a.y + b.y);
    o[2] = (f16)(a.z + b.z); o[3] = (f16)(a.w + b.w);
    *(f16x4*)&out[(long)i * 4] = o;
}

// --- split-f16 GEMM: C = act(A @ B^T_stored + bias) ------------------------
// Tile 64x128, BK=64, 4 waves each owning 32x64 (2x4 frags of 16x16x32).
// Staging via global_load_lds (linear LDS dest, pre-swizzled global source;
// read side applies the same chunk^=row&7 involution). Single-buffered,
// 3-6 blocks/CU -- inter-block overlap hides barrier drains (m114).
// OUTM: 0 pair write, 1 pair write transposed, 2 f32 write, 3 f32 accum,
//       5 score mode (flat expert=col0>>9; XCD y-chunk swizzle; row-dot KQ2
//         -> atomicAdd) + write t1 single-f16 to Ch (U), 6 f32 transposed,
//       7 single-f16 write transposed, 9 single-f16 plain write,
//       10 split-K mixture (XCD row-panel swizzle; z=0: Cf += v non-atomic
//          into wb-seeded buffer; z=1: Cf2 (=Cl recast) plain write).
// AMODE: 0 = A pair (gload, 3rd MFMA), 1 = A single (gload),
//        2 = A single reg-staged with fused per-(row, k-block) wscale.
// BSINGLE: B single plane (skips the AhBl MFMA).
template <int OUTM, bool RELU, int AMODE, bool BSINGLE>
__global__ __launch_bounds__(256, (AMODE == 0 && !BSINGLE) ? 3 : (AMODE == 0 ? 4 : 6))
void gemm_pair(
    const f16* __restrict__ Ah, const f16* __restrict__ Al, int lda, long zsA,
    const f16* __restrict__ Bh, const f16* __restrict__ Bl, int ldb, long zsB,
    const float* __restrict__ bias, long zsBias,
    f16* __restrict__ Ch, f16* __restrict__ Cl, float* __restrict__ Cf,
    int ldc, long zsC, int K,
    const float* __restrict__ wscale,
    const int* __restrict__ task, const float* __restrict__ KQ2,
    float* __restrict__ scores) {
    __shared__ f16 As[AMODE == 0 ? 2 : 1][64][64];
    __shared__ f16 Bs[BSINGLE ? 1 : 2][128][64];
    const int z = blockIdx.z;
    Ah += (long)z * zsA;
    if constexpr (AMODE == 0) Al += (long)z * zsA;
    Bh += (long)z * zsB;
    if constexpr (!BSINGLE) Bl += (long)z * zsB;
    if (bias) bias += (long)z * zsBias;
    if (OUTM <= 1) { Ch += (long)z * zsC; Cl += (long)z * zsC; }
    if (OUTM == 7 || OUTM == 9) { Ch += (long)z * zsC; }
    if (OUTM == 2 || OUTM == 3 || OUTM == 6) { Cf += (long)z * zsC; }
    if constexpr (OUTM == 10) { if (wscale) wscale += (long)z * 8; }
    const int tid = threadIdx.x;
    const int l = tid & 63;
    const int w = tid >> 6;
    int bx = blockIdx.x, by = blockIdx.y;
    if constexpr (OUTM == 5) {
        // XCD y-chunk swizzle (R10-verified): grid (128,64); each XCD owns 8
        // contiguous col-tiles -> its B pair working set stays L2-resident.
        const int id = by * gridDim.x + bx;
        const int xcd = id & 7, r = id >> 3;
        by = (xcd << 3) | (r & 7);
        bx = r >> 3;
    }
    if constexpr (OUTM == 10) {
        // XCD row-panel swizzle: grid (128,4); 4 consecutive same-XCD blocks
        // share one 1MB A row-panel -> L2-resident reuse (A fetch /4).
        const int fid = by * gridDim.x + bx;
        const int xcd = fid & 7, k = fid >> 3;   // k in 0..63
        bx = xcd * 16 + (k >> 2);
        by = k & 3;
    }
    const int row0 = bx * 64;
    const int col0 = by * 128;
    const int wr = (w >> 1) * 32;
    const int wc = (w & 1) * 64;
    const int grow = l >> 3;           // row within 8-row group
    const int gch = (l & 7) ^ grow;    // pre-swizzled k-chunk for gload_lds

    f32x4 acc[2][4];
#pragma unroll
    for (int mi = 0; mi < 2; ++mi)
#pragma unroll
        for (int ni = 0; ni < 4; ++ni)
#pragma unroll
            for (int j = 0; j < 4; ++j) acc[mi][ni][j] = 0.f;

    // AMODE==2: reg-staged A with fused per-(row, k-block) scale
    uint4 areg0, areg1; float ascl0, ascl1;
    auto ldA = [&](int k0) {
        const int r0 = w * 16 + grow, r1 = r0 + 8;
        const int scl = l & 7;
        areg0 = *(const uint4*)&Ah[(long)(row0 + r0) * lda + k0 + scl * 8];
        areg1 = *(const uint4*)&Ah[(long)(row0 + r1) * lda + k0 + scl * 8];
        const int e = k0 >> 9;
        ascl0 = wscale[(long)(row0 + r0) * 16 + e];
        ascl1 = wscale[(long)(row0 + r1) * 16 + e];
    };
    auto wrA = [&]() {
        const int scl = l & 7;
#pragma unroll
        for (int h = 0; h < 2; ++h) {
            const int r = w * 16 + grow + h * 8;
            const float s = h ? ascl1 : ascl0;
            f16x8 v = h ? *(f16x8*)&areg1 : *(f16x8*)&areg0;
#pragma unroll
            for (int j = 0; j < 8; ++j) v[j] = (f16)((float)v[j] * s);
            *(uint4*)&As[0][r][(scl ^ (r & 7)) * 8] = *(uint4*)&v;
        }
    };

    if constexpr (AMODE == 2) ldA(0);
    for (int k0 = 0; k0 < K; k0 += 64) {
        __syncthreads();
        if constexpr (AMODE == 2) {
            wrA();
            if (k0 + 64 < K) ldA(k0 + 64);  // next loads issued early (hidden under compute)
        } else {
            // A: wave w stages rows [w*16, w*16+16)
            const long ga = (long)(row0 + w * 16 + grow) * lda + k0 + gch * 8;
            gload16(Ah + ga, &As[0][w * 16][0]);
            gload16(Ah + ga + (long)8 * lda, &As[0][w * 16 + 8][0]);
            if constexpr (AMODE == 0) {
                gload16(Al + ga, &As[1][w * 16][0]);
                gload16(Al + ga + (long)8 * lda, &As[1][w * 16 + 8][0]);
            }
        }
        {
            // B: wave w stages rows [w*32, w*32+32)
            const long gb = (long)(col0 + w * 32 + grow) * ldb + k0 + gch * 8;
            gload16(Bh + gb, &Bs[0][w * 32][0]);
            gload16(Bh + gb + (long)8 * ldb, &Bs[0][w * 32 + 8][0]);
            gload16(Bh + gb + (long)16 * ldb, &Bs[0][w * 32 + 16][0]);
            gload16(Bh + gb + (long)24 * ldb, &Bs[0][w * 32 + 24][0]);
            if constexpr (!BSINGLE) {
                gload16(Bl + gb, &Bs[1][w * 32][0]);
                gload16(Bl + gb + (long)8 * ldb, &Bs[1][w * 32 + 8][0]);
                gload16(Bl + gb + (long)16 * ldb, &Bs[1][w * 32 + 16][0]);
                gload16(Bl + gb + (long)24 * ldb, &Bs[1][w * 32 + 24][0]);
            }
        }
        __syncthreads();
        const int r16 = l & 15, kg = l >> 4;
#pragma unroll
        for (int ks = 0; ks < 2; ++ks) {
            f16x8 a_h[2], a_l[2], b_h[4], b_l[4];
#pragma unroll
            for (int mi = 0; mi < 2; ++mi) {
                const int r = wr + mi * 16 + r16;
                const int off = ((ks * 4 + kg) ^ (r & 7)) * 8;
                a_h[mi] = *(const f16x8*)&As[0][r][off];
                if constexpr (AMODE == 0) a_l[mi] = *(const f16x8*)&As[1][r][off];
            }
#pragma unroll
            for (int ni = 0; ni < 4; ++ni) {
                const int c = wc + ni * 16 + r16;
                const int off = ((ks * 4 + kg) ^ (c & 7)) * 8;
                b_h[ni] = *(const f16x8*)&Bs[0][c][off];
                if constexpr (!BSINGLE) b_l[ni] = *(const f16x8*)&Bs[1][c][off];
            }
#pragma unroll
            for (int mi = 0; mi < 2; ++mi)
#pragma unroll
                for (int ni = 0; ni < 4; ++ni) {
                    acc[mi][ni] = __builtin_amdgcn_mfma_f32_16x16x32_f16(a_h[mi], b_h[ni], acc[mi][ni], 0, 0, 0);
                    if constexpr (!BSINGLE)
                        acc[mi][ni] = __builtin_amdgcn_mfma_f32_16x16x32_f16(a_h[mi], b_l[ni], acc[mi][ni], 0, 0, 0);
                    if constexpr (AMODE == 0)
                        acc[mi][ni] = __builtin_amdgcn_mfma_f32_16x16x32_f16(a_l[mi], b_h[ni], acc[mi][ni], 0, 0, 0);
                }
        }
    }
    // epilogue. C layout (m89-verified): col = lane&15, row = (lane>>4)*4 + reg.
    const int lane15 = l & 15;
    const int rsub = (l >> 4) * 4;
    if (OUTM == 5) {
        const int expert = col0 >> 9;
        float bv[4];
#pragma unroll
        for (int ni = 0; ni < 4; ++ni)
            bv[ni] = bias ? bias[col0 + wc + ni * 16 + lane15] : 0.f;
#pragma unroll
        for (int mi = 0; mi < 2; ++mi)
#pragma unroll
            for (int j = 0; j < 4; ++j) {
                const int rowg = row0 + wr + mi * 16 + rsub + j;
                const int t = task[rowg];
                const float* kqr = KQ2 + ((long)t * 16 + expert) * 512;
                float part = 0.f;
#pragma unroll
                for (int ni = 0; ni < 4; ++ni) {
                    const int colg = col0 + wc + ni * 16 + lane15;
                    float v = acc[mi][ni][j] + bv[ni];
                    if (RELU) v = fmaxf(v, 0.f);
                    Ch[(long)rowg * ldc + colg] = (f16)v;
                    part += v * kqr[colg & 511];
                }
#pragma unroll
                for (int d = 1; d < 16; d <<= 1) part += __shfl_xor(part, d);
                if (lane15 == 0) atomicAdd(&scores[rowg * 16 + expert], part);
            }
    } else {
        float* Cf2 = (float*)Cl;  // OUTM==10 partition-1 output
#pragma unroll
        for (int mi = 0; mi < 2; ++mi)
#pragma unroll
            for (int ni = 0; ni < 4; ++ni) {
                const int colg = col0 + wc + ni * 16 + lane15;
                const float bv = bias ? bias[colg] : 0.f;
#pragma unroll
                for (int j = 0; j < 4; ++j) {
                    const int rowg = row0 + wr + mi * 16 + rsub + j;
                    float v = acc[mi][ni][j] + bv;
                    if (RELU) v = fmaxf(v, 0.f);
                    if (OUTM == 0) {
                        f16 hh, ll; fsplit(v, hh, ll);
                        const long idx = (long)rowg * ldc + colg;
                        Ch[idx] = hh; Cl[idx] = ll;
                    } else if (OUTM == 1) {
                        f16 hh, ll; fsplit(v, hh, ll);
                        const long idx = (long)colg * ldc + rowg;
                        Ch[idx] = hh; Cl[idx] = ll;
                    } else if (OUTM == 2) {
                        Cf[(long)rowg * ldc + colg] = v;
                    } else if (OUTM == 3) {
                        Cf[(long)rowg * ldc + colg] += v;
                    } else if (OUTM == 6) {
                        Cf[(long)colg * ldc + rowg] = v;
                    } else if (OUTM == 7) {
                        Ch[(long)colg * ldc + rowg] = (f16)v;
                    } else if (OUTM == 9) {
                        Ch[(long)rowg * ldc + colg] = (f16)v;
                    } else if (OUTM == 10) {
                        const long idx = (long)rowg * ldc + colg;
                        if (z == 0) Cf[idx] += v;   // wb-seeded, tiles disjoint
                        else Cf2[idx] = v;
                    }
                }
            }
    }
}

// --- softmax over E=16 per row; adds cb[task[b]] (scores pre-zeroed) -------
__global__ void softmax16(float* __restrict__ sc, const int* __restrict__ task,
                          const float* __restrict__ cb) {
    const int b = blockIdx.x * 256 + threadIdx.x;  // 8192
    const float* cbr = cb + task[b] * 16;
    float v[16];
    const float4* pp = (const float4*)&sc[b * 16];
    const float4* cp = (const float4*)cbr;
#pragma unroll
    for (int qq = 0; qq < 4; ++qq) {
        float4 t = pp[qq];
        float4 c = cp[qq];
        v[qq * 4] = t.x + c.x; v[qq * 4 + 1] = t.y + c.y;
        v[qq * 4 + 2] = t.z + c.z; v[qq * 4 + 3] = t.w + c.w;
    }
    float m = v[0];
#pragma unroll
    for (int e = 1; e < 16; ++e) m = fmaxf(m, v[e]);
    float ssum = 0.f;
#pragma unroll
    for (int e = 0; e < 16; ++e) { v[e] = expf(v[e] - m); ssum += v[e]; }
    const float inv = 1.f / ssum;
    float4* o = (float4*)&sc[b * 16];
#pragma unroll
    for (int qq = 0; qq < 4; ++qq) {
        float4 t;
        t.x = v[qq * 4] * inv; t.y = v[qq * 4 + 1] * inv;
        t.z = v[qq * 4 + 2] * inv; t.w = v[qq * 4 + 3] * inv;
        o[qq] = t;
    }
}

// --- towerAcc[b][j] = sum_e w[b][e] * b2V[e][j] ----------------------------
__global__ void wb_init(const float* __restrict__ w, const float* __restrict__ b2V,
                        float* __restrict__ towerAcc) {
    const int b = blockIdx.x;
    const int tid = threadIdx.x;
    float wv[16];
#pragma unroll
    for (int e = 0; e < 16; ++e) wv[e] = w[b * 16 + e];
#pragma unroll
    for (int rep = 0; rep < 2; ++rep) {
        const int j = rep * 256 + tid;
        float s = 0.f;
#pragma unroll
        for (int e = 0; e < 16; ++e) s += wv[e] * b2V[e * 512 + j];
        towerAcc[(long)b * 512 + j] = s;
    }
}

// --- final heads: GEMV vs W2T (float4 streams), squash, logp ---------------
// Rcat: [8192][1024] single f16; cols 0..511 = mu path, 512..1023 = ls path.
__global__ void head_kernel2(
    const f16* __restrict__ Rh,
    const float* __restrict__ W2T,   // [2][32][512]
    const float* __restrict__ mb2, const float* __restrict__ lb2,
    const float* __restrict__ eps, float* __restrict__ pi, float* __restrict__ logp) {
    __shared__ float src[4][1032];
    const int tid = threadIdx.x, l = tid & 63, w = tid >> 6;
    const int b = blockIdx.x * 4 + w;  // one wave per row
    const long rb = (long)b * 1024;
    {
        f16x8 h0 = *(const f16x8*)&Rh[rb + l * 8];
        f16x8 h1 = *(const f16x8*)&Rh[rb + 512 + l * 8];
#pragma unroll
        for (int j = 0; j < 8; ++j) {
            src[w][l * 8 + j] = (float)h0[j];
            src[w][512 + l * 8 + j] = (float)h1[j];
        }
    }
    __syncthreads();
    const int col = l & 31;
    const int half = l >> 5;  // 0 = mu, 1 = log_std
    const float4* wp = (const float4*)(W2T + ((long)(half * 32 + col)) * 512);
    const float4* sp = (const float4*)(&src[w][half * 512]);
    float a0 = 0.f, a1 = 0.f, a2 = 0.f, a3 = 0.f;
#pragma unroll 8
    for (int k4 = 0; k4 < 128; ++k4) {
        const float4 wv = wp[k4];
        const float4 sv = sp[k4];
        a0 = fmaf(wv.x, sv.x, a0);
        a1 = fmaf(wv.y, sv.y, a1);
        a2 = fmaf(wv.z, sv.z, a2);
        a3 = fmaf(wv.w, sv.w, a3);
    }
    const float* b2 = half ? lb2 : mb2;
    float s = b2[col] + ((a0 + a1) + (a2 + a3));
    const float other = __shfl_xor(s, 32);  // swap mu <-> log_std halves
    if (half == 0) {
        const float mu = s;
        float ls = fminf(fmaxf(other, -20.f), 2.f);
        const float e = eps[(long)b * 32 + col];
        const float a = mu + expf(ls) * e;
        float lt = -0.5f * e * e - ls - 0.91893853320467274f;  // -0.5*log(2*pi)
        const float x = -2.f * a;
        const float sp2 = fmaxf(x, 0.f) + log1pf(expf(-fabsf(x)));
        lt -= 2.f * (0.69314718055994531f - a - sp2);
        pi[(long)b * 32 + col] = tanhf(a);
        float r = lt;
#pragma unroll
        for (int d = 1; d < 32; d <<= 1) r += __shfl_xor(r, d);
        if (col == 0) logp[b] = r;
    }
}

// ---------------------------------------------------------------------------
extern "C" void kernel_launch(void* const* d_in, const int* in_sizes, int n_in,
                              void* d_out, int out_size, void* d_ws, size_t ws_size,
                              hipStream_t stream) {
    const float* obs = (const float*)d_in[0];
    const int* task = (const int*)d_in[1];
    const float* eps = (const float*)d_in[2];
    const float* bW1 = (const float*)d_in[3];
    const float* bb1 = (const float*)d_in[4];
    const float* bW2 = (const float*)d_in[5];
    const float* bb2 = (const float*)d_in[6];
    const float* eW1 = (const float*)d_in[7];
    const float* eb1 = (const float*)d_in[8];
    const float* eW2 = (const float*)d_in[9];
    const float* eb2 = (const float*)d_in[10];
    const float* keyM = (const float*)d_in[11];
    const float* valM = (const float*)d_in[12];
    const float* tq = (const float*)d_in[13];
    const float* mW1 = (const float*)d_in[14];
    const float* mb1 = (const float*)d_in[15];
    const float* mW2 = (const float*)d_in[16];
    const float* mb2 = (const float*)d_in[17];
    const float* lW1 = (const float*)d_in[18];
    const float* lb1 = (const float*)d_in[19];
    const float* lW2 = (const float*)d_in[20];
    const float* lb2 = (const float*)d_in[21];
    (void)in_sizes; (void)n_in; (void)out_size; (void)ws_size;

    // ---- workspace map (base 122 MB + 128 MB U; ws >= 251 MB verified R4) --
    const size_t MB = 1u << 20, KB = 1u << 10;
    char* base = (char*)d_ws;
    f16* eW1t_h = (f16*)(base + 0 * MB);   f16* eW1t_l = (f16*)(base + 8 * MB);
    f16* Wv2_h  = (f16*)(base + 16 * MB);  // [j2][(e,i)] single f16
    f16* eW2s_h = (f16*)(base + 32 * MB);  f16* eW2s_l = (f16*)(base + 40 * MB);
    f16* h2_h   = (f16*)(base + 32 * MB);  f16* h2_l   = (f16*)(base + 40 * MB);  // after folds
    f16* t1_h   = (f16*)(base + 48 * MB);  f16* t1_l   = (f16*)(base + 56 * MB);
    f16* Rcat   = (f16*)(base + 48 * MB);                                         // heads (t1 dead), 16 MB single
    f16* Vt_h   = (f16*)(base + 64 * MB);  f16* Vt_l   = (f16*)(base + 72 * MB);
    float* towerAcc2 = (float*)(base + 64 * MB);                                  // phase 2 (Vt dead), 16 MB
    // 80-112 MB region, phase 1 (KQ path): keyM pairs, KqT, tqP, KQ2
    f16* keyMs_h = (f16*)(base + 80 * MB); f16* keyMs_l = (f16*)(base + 88 * MB);
    f16* KqT_h   = (f16*)(base + 96 * MB); f16* KqT_l   = (f16*)(base + 98 * MB); // [128][8192]
    f16* tqP_h   = (f16*)(base + 100 * MB); f16* tqP_l  = (f16*)(base + 100 * MB + 128 * KB); // [128][512]
    float* KQ2   = (float*)(base + 104 * MB);                                     // [128][16][512] f32
    // 80-112 MB region, phase 2 (tower/heads): towerAcc (wb), twP (single)
    float* towerAcc = (float*)(base + 80 * MB);                                   // 16 MB
    f16* twP_h  = (f16*)(base + 96 * MB);
    f16* obs_h  = (f16*)(base + 112 * MB); f16* obs_l  = (f16*)(base + 114 * MB);
    char* q = base + 116 * MB;
    f16* bW1t_h = (f16*)q; q += 128 * KB;  f16* bW1t_l = (f16*)q; q += 128 * KB;
    f16* bW2t_h = (f16*)q; q += 512 * KB;  f16* bW2t_l = (f16*)q; q += 512 * KB;
    // order m_h, l_h, m_l, l_l so the z=2 head GEMM can stride (zsB = 262144)
    f16* mW1t_h = (f16*)q; q += 512 * KB;
    f16* lW1t_h = (f16*)q; q += 512 * KB;
    f16* mW1t_l = (f16*)q; q += 512 * KB;
    f16* lW1t_l = (f16*)q; q += 512 * KB;
    float* scores = (float*)q; q += 512 * KB;    // 8192*16 f32 (becomes w)
    float* b2V    = (float*)q; q += 32 * KB;
    float* cb     = (float*)q; q += 16 * KB;
    float* W2T    = (float*)q; q += 128 * KB;    // [2][32][512]
    float* bcat   = (float*)q; q += 16 * KB;     // [2][512]
    f16* U = (f16*)(base + 122 * MB);            // [8192][8192] single f16

    const long EST = 262144;  // per-expert 512x512 stride

    // ---- 1) splits / transposes ----
    hipMemsetAsync(tqP_h, 0, 256 * KB, stream);   // tqP_h and tqP_l contiguous
    hipMemsetAsync(scores, 0, 512 * KB, stream);  // passA atomicAdd target
    split_pairs4<<<9241, 256, 0, stream>>>(eW2, eW2s_h, eW2s_l, keyM, keyMs_h, keyMs_l,
                                           obs, obs_h, obs_l, tq, tqP_h, tqP_l);
    transpose_split6<<<dim3(16, 16, 36), 256, 0, stream>>>(
        eW1, valM, bW2, mW1, lW1, bW1, eW1t_h, eW1t_l, Vt_h, Vt_l,
        bW2t_h, bW2t_l, mW1t_h, mW1t_l, lW1t_h, lW1t_l, bW1t_h, bW1t_l);
    build_w2t_bcat<<<132, 256, 0, stream>>>(mW2, lW2, mb1, lb1, W2T, bcat);

    // ---- 2) attention folds ----
    // Wv2[j2][(e,i)] = (eW2@V)[i][j2]  (single-f16 out -> 2-MFMA: A pair x B single)
    gemm_pair<7, false, 0, true><<<dim3(8, 4, 16), 256, 0, stream>>>(
        eW2s_h, eW2s_l, 512, EST, Vt_h, nullptr, 512, EST, nullptr, 0,
        Wv2_h, nullptr, nullptr, 8192, 512, 512, nullptr, nullptr, nullptr, nullptr);
    // KqT[t][(e,k)] = (keyM @ tq^T)[(e,k)][t]   (N=128 padded, pair transposed)
    gemm_pair<1, false, 0, false><<<dim3(128, 1, 1), 256, 0, stream>>>(
        keyMs_h, keyMs_l, 512, 0, tqP_h, tqP_l, 512, 0, nullptr, 0,
        KqT_h, KqT_l, nullptr, 8192, 0, 512, nullptr, nullptr, nullptr, nullptr);
    // KQ2[(t,e)][i] = (eW2_e @ KqT_e^T)[i][t]   (f32 transposed write)
    gemm_pair<6, false, 0, false><<<dim3(8, 1, 16), 256, 0, stream>>>(
        eW2s_h, eW2s_l, 512, EST, KqT_h, KqT_l, 8192, 512, nullptr, 0,
        nullptr, nullptr, KQ2, 8192, 512, 512, nullptr, nullptr, nullptr, nullptr);
    fold_misc<<<232, 256, 0, stream>>>(eb2, valM, KqT_h, KqT_l, b2V, cb);

    // ---- 3) backbone (full pair precision: feeds the score path) ----
    gemm_pair<0, true, 0, false><<<dim3(128, 4, 1), 256, 0, stream>>>(
        obs_h, obs_l, 128, 0, bW1t_h, bW1t_l, 128, 0, bb1, 0,
        t1_h, t1_l, nullptr, 512, 0, 128, nullptr, nullptr, nullptr, nullptr);
    gemm_pair<0, true, 0, false><<<dim3(128, 4, 1), 256, 0, stream>>>(
        t1_h, t1_l, 512, 0, bW2t_h, bW2t_l, 512, 0, bb2, 0,
        h2_h, h2_l, nullptr, 512, 0, 512, nullptr, nullptr, nullptr, nullptr);

    // ---- 4) pass A: one flat M=8192 x N=8192 GEMM; scores + U ----
    gemm_pair<5, true, 0, false><<<dim3(128, 64, 1), 256, 0, stream>>>(
        h2_h, h2_l, 512, 0, eW1t_h, eW1t_l, 512, 0, eb1, 0,
        U, nullptr, nullptr, 8192, 0, 512, nullptr, task, KQ2, scores);
    softmax16<<<32, 256, 0, stream>>>(scores, task, cb);

    // ---- 5) tower: split-K=2, atomic-free (z=0 RMW wb-seeded towerAcc,
    //         z=1 plain-writes towerAcc2), then sum+convert to f16 ----
    wb_init<<<8192, 256, 0, stream>>>(scores, b2V, towerAcc);
    gemm_pair<10, false, 2, true><<<dim3(128, 4, 2), 256, 0, stream>>>(
        U, nullptr, 8192, 4096, Wv2_h, nullptr, 8192, 4096, nullptr, 0,
        nullptr, (f16*)towerAcc2, towerAcc, 512, 0, 4096, scores, nullptr, nullptr, nullptr);
    tw_convert<<<4096, 256, 0, stream>>>(towerAcc, towerAcc2, twP_h);

    // ---- 6) heads: layer-1 (single x single = 1 MFMA) into Rcat, GEMV+squash --
    gemm_pair<9, true, 1, true><<<dim3(128, 4, 2), 256, 0, stream>>>(
        twP_h, nullptr, 512, 0, mW1t_h, nullptr, 512, 262144, bcat, 512,
        Rcat, nullptr, nullptr, 1024, 512, 512, nullptr, nullptr, nullptr, nullptr);
    head_kernel2<<<2048, 256, 0, stream>>>(Rcat, W2T, mb2, lb2, eps,
                                           (float*)d_out, (float*)d_out + 262144);
}

// Round 15
// 626.898 us; speedup vs baseline: 1.0674x; 1.0068x over previous
//
#include <hip/hip_runtime.h>
#include <hip/hip_bf16.h>
#include <cstdint>

// ---------------------------------------------------------------------------
// SquashedGaussianMoEActor forward, MI355X (gfx950).
// Split-f16 MFMA = fp32-quality on the score path (softmax flip-sensitivity
// forbids fewer than 3 MFMAs there); single-f16 tower path (error budget
// verified: absmax 4.0 vs threshold 14.56, R6-R14).
// R15: wb folded into tw_finish (wb_init dispatch + towerAcc RMW deleted;
// both split-K partitions plain-write). passA untouched (249us @ 37.7%
// MfmaUtil, XCD-swizzled -- this schedule's proven structural floor).
// B=8192, OBS=128, H=D=512, E=16, T=50, A=32.
// ---------------------------------------------------------------------------

typedef _Float16 f16;
typedef _Float16 f16x4 __attribute__((ext_vector_type(4)));
typedef _Float16 f16x8 __attribute__((ext_vector_type(8)));
typedef float f32x4 __attribute__((ext_vector_type(4)));

__device__ __forceinline__ void fsplit(float x, f16& h, f16& l) {
    h = (f16)x;
    l = (f16)(x - (float)h);
}

__device__ __forceinline__ void gload16(const void* g, void* s) {
    __builtin_amdgcn_global_load_lds(
        (const __attribute__((address_space(1))) void*)g,
        (__attribute__((address_space(3))) void*)s, 16, 0, 0);
}

// --- eW2 + keyM + obs + tq splits in one dispatch --------------------------
// grid 9241 x 256 = 2365696 = 1048576 + 1048576 + 262144 + 6400 (exact).
__global__ void split_pairs4(const float* __restrict__ xa, f16* __restrict__ ha,
                             f16* __restrict__ la, const float* __restrict__ xb,
                             f16* __restrict__ hb, f16* __restrict__ lb,
                             const float* __restrict__ xc, f16* __restrict__ hc,
                             f16* __restrict__ lc, const float* __restrict__ xd,
                             f16* __restrict__ hd, f16* __restrict__ ld) {
    long i = (long)blockIdx.x * 256 + threadIdx.x;
    const float* x; f16* h; f16* l;
    if (i < 1048576) { x = xa; h = ha; l = la; }
    else if (i < 2097152) { i -= 1048576; x = xb; h = hb; l = lb; }
    else if (i < 2359296) { i -= 2097152; x = xc; h = hc; l = lc; }
    else { i -= 2359296; x = xd; h = hd; l = ld; }
    float4 v = ((const float4*)x)[i];
    float a[4] = {v.x, v.y, v.z, v.w};
    f16x4 hh, ll;
#pragma unroll
    for (int j = 0; j < 4; ++j) { f16 hj, lj; fsplit(a[j], hj, lj); hh[j] = hj; ll[j] = lj; }
    *(f16x4*)&h[i * 4] = hh;
    *(f16x4*)&l[i * 4] = ll;
}

// --- six weight transposes in one dispatch (z = 0..35) ---------------------
// z<16: eW1_e, z<32: valM_e, 32: bW2, 33: mW1, 34: lW1, 35: bW1 (K=128).
__global__ void transpose_split6(
    const float* __restrict__ eW1, const float* __restrict__ valM,
    const float* __restrict__ bW2, const float* __restrict__ mW1,
    const float* __restrict__ lW1, const float* __restrict__ bW1,
    f16* __restrict__ eW1t_h, f16* __restrict__ eW1t_l,
    f16* __restrict__ Vt_h, f16* __restrict__ Vt_l,
    f16* __restrict__ bW2t_h, f16* __restrict__ bW2t_l,
    f16* __restrict__ mW1t_h, f16* __restrict__ mW1t_l,
    f16* __restrict__ lW1t_h, f16* __restrict__ lW1t_l,
    f16* __restrict__ bW1t_h, f16* __restrict__ bW1t_l) {
    __shared__ float t[32][33];
    const int z = blockIdx.z;
    const float* W; f16* Th; f16* Tl; int Kd = 512;
    if (z < 16) { W = eW1 + (long)z * 262144; Th = eW1t_h + (long)z * 262144; Tl = eW1t_l + (long)z * 262144; }
    else if (z < 32) { const int e = z - 16; W = valM + (long)e * 262144; Th = Vt_h + (long)e * 262144; Tl = Vt_l + (long)e * 262144; }
    else if (z == 32) { W = bW2; Th = bW2t_h; Tl = bW2t_l; }
    else if (z == 33) { W = mW1; Th = mW1t_h; Tl = mW1t_l; }
    else if (z == 34) { W = lW1; Th = lW1t_h; Tl = lW1t_l; }
    else { W = bW1; Th = bW1t_h; Tl = bW1t_l; Kd = 128; if (blockIdx.x >= 4) return; }
    const int k0 = blockIdx.x * 32, n0 = blockIdx.y * 32;
    const int tid = threadIdx.x;
    const int r = tid >> 3, c4 = (tid & 7) * 4;
    float4 v = *(const float4*)&W[(long)(k0 + r) * 512 + n0 + c4];
    t[r][c4] = v.x; t[r][c4 + 1] = v.y; t[r][c4 + 2] = v.z; t[r][c4 + 3] = v.w;
    __syncthreads();
    f16x4 hh, ll;
#pragma unroll
    for (int j = 0; j < 4; ++j) { f16 hj, lj; fsplit(t[c4 + j][r], hj, lj); hh[j] = hj; ll[j] = lj; }
    const long ob = (long)(n0 + r) * Kd + k0 + c4;
    *(f16x4*)&Th[ob] = hh;
    *(f16x4*)&Tl[ob] = ll;
}

// --- W2T[half][col][k] + bcat = [mb1;lb1] in one dispatch ------------------
__global__ void build_w2t_bcat(const float* __restrict__ mW2, const float* __restrict__ lW2,
                               const float* __restrict__ mb1, const float* __restrict__ lb1,
                               float* __restrict__ W2T, float* __restrict__ bcat) {
    const int i = blockIdx.x * 256 + threadIdx.x;  // grid 132 -> 33792
    if (i < 32768) {
        const int half = i >> 14, col = (i >> 9) & 31, k = i & 511;
        const float* src = half ? lW2 : mW2;
        W2T[i] = src[k * 32 + col];
    } else {
        const int j = i - 32768;
        if (j < 1024) bcat[j] = (j < 512) ? mb1[j] : lb1[j - 512];
    }
}

// --- b2V fold + cb-from-Kq in one dispatch ---------------------------------
__global__ void fold_misc(const float* __restrict__ eb2, const float* __restrict__ valM,
                          const f16* __restrict__ KqT_h, const f16* __restrict__ KqT_l,
                          float* __restrict__ b2V, float* __restrict__ cb) {
    if (blockIdx.x < 32) {
        const int gid = blockIdx.x * 256 + threadIdx.x;  // 8192
        const int e = gid >> 9, j = gid & 511;
        const float* Me = valM + (long)e * 262144;
        const float* be = eb2 + e * 512;
        float s = 0.f;
        for (int k = 0; k < 512; ++k) s += be[k] * Me[(long)k * 512 + j];
        b2V[gid] = s;
    } else {
        const int gw = ((blockIdx.x - 32) * 256 + threadIdx.x) >> 6;  // 0..799
        const int l = threadIdx.x & 63;
        const int t = gw >> 4, e = gw & 15;
        const long base = (long)t * 8192 + e * 512 + l * 8;
        f16x8 hh = *(const f16x8*)&KqT_h[base];
        f16x8 ll = *(const f16x8*)&KqT_l[base];
        const float* bb = eb2 + e * 512 + l * 8;
        float s = 0.f;
#pragma unroll
        for (int j = 0; j < 8; ++j) s += ((float)hh[j] + (float)ll[j]) * bb[j];
#pragma unroll
        for (int d = 1; d < 64; d <<= 1) s += __shfl_xor(s, d);
        if (l == 0) cb[t * 16 + e] = s;
    }
}

// --- twP = (f16)(acc1 + acc2 + sum_e w[b,e]*b2V[e,j])  (wb folded in) ------
__global__ void tw_finish(const float* __restrict__ acc1, const float* __restrict__ acc2,
                          const float* __restrict__ w, const float* __restrict__ b2V,
                          f16* __restrict__ out) {
    const int i = blockIdx.x * 256 + threadIdx.x;  // 1048576 float4 groups
    const int b = i >> 7, jg = i & 127;            // row b, 4-col group jg
    float4 a = ((const float4*)acc1)[i];
    float4 c = ((const float4*)acc2)[i];
    float s0 = a.x + c.x, s1 = a.y + c.y, s2 = a.z + c.z, s3 = a.w + c.w;
    const float4* bv = (const float4*)b2V;         // [16][128] float4 groups (32 KB, L2)
    const float* wr = w + b * 16;
#pragma unroll
    for (int e = 0; e < 16; ++e) {
        const float we = wr[e];
        const float4 vv = bv[e * 128 + jg];
        s0 = fmaf(we, vv.x, s0); s1 = fmaf(we, vv.y, s1);
        s2 = fmaf(we, vv.z, s2); s3 = fmaf(we, vv.w, s3);
    }
    f16x4 o; o[0] = (f16)s0; o[1] = (f16)s1; o[2] = (f16)s2; o[3] = (f16)s3;
    *(f16x4*)&out[(long)i * 4] = o;
}

// --- split-f16 GEMM: C = act(A @ B^T_stored + bias) ------------------------
// Tile 64x128, BK=64, 4 waves each owning 32x64 (2x4 frags of 16x16x32).
// Staging via global_load_lds (linear LDS dest, pre-swizzled global source;
// read side applies the same chunk^=row&7 involution). Single-buffered,
// 3-6 blocks/CU -- inter-block overlap hides barrier drains (m114).
// OUTM: 0 pair write, 1 pair write transposed, 2 f32 write, 3 f32 accum,
//       5 score mode (flat expert=col0>>9; XCD y-chunk swizzle; row-dot KQ2
//         -> atomicAdd) + write t1 single-f16 to Ch (U), 6 f32 transposed,
//       7 single-f16 write transposed, 9 single-f16 plain write,
//       10 split-K mixture (XCD row-panel swizzle; z=0 -> Cf plain write,
//          z=1 -> Cf2 (=Cl recast) plain write; summed in tw_finish).
// AMODE: 0 = A pair (gload, 3rd MFMA), 1 = A single (gload),
//        2 = A single reg-staged with fused per-(row, k-block) wscale.
// BSINGLE: B single plane (skips the AhBl MFMA).
template <int OUTM, bool RELU, int AMODE, bool BSINGLE>
__global__ __launch_bounds__(256, (AMODE == 0 && !BSINGLE) ? 3 : (AMODE == 0 ? 4 : 6))
void gemm_pair(
    const f16* __restrict__ Ah, const f16* __restrict__ Al, int lda, long zsA,
    const f16* __restrict__ Bh, const f16* __restrict__ Bl, int ldb, long zsB,
    const float* __restrict__ bias, long zsBias,
    f16* __restrict__ Ch, f16* __restrict__ Cl, float* __restrict__ Cf,
    int ldc, long zsC, int K,
    const float* __restrict__ wscale,
    const int* __restrict__ task, const float* __restrict__ KQ2,
    float* __restrict__ scores) {
    __shared__ f16 As[AMODE == 0 ? 2 : 1][64][64];
    __shared__ f16 Bs[BSINGLE ? 1 : 2][128][64];
    const int z = blockIdx.z;
    Ah += (long)z * zsA;
    if constexpr (AMODE == 0) Al += (long)z * zsA;
    Bh += (long)z * zsB;
    if constexpr (!BSINGLE) Bl += (long)z * zsB;
    if (bias) bias += (long)z * zsBias;
    if (OUTM <= 1) { Ch += (long)z * zsC; Cl += (long)z * zsC; }
    if (OUTM == 7 || OUTM == 9) { Ch += (long)z * zsC; }
    if (OUTM == 2 || OUTM == 3 || OUTM == 6) { Cf += (long)z * zsC; }
    if constexpr (OUTM == 10) { if (wscale) wscale += (long)z * 8; }
    const int tid = threadIdx.x;
    const int l = tid & 63;
    const int w = tid >> 6;
    int bx = blockIdx.x, by = blockIdx.y;
    if constexpr (OUTM == 5) {
        // XCD y-chunk swizzle (R10-verified): grid (128,64); each XCD owns 8
        // contiguous col-tiles -> its B pair working set stays L2-resident.
        const int id = by * gridDim.x + bx;
        const int xcd = id & 7, r = id >> 3;
        by = (xcd << 3) | (r & 7);
        bx = r >> 3;
    }
    if constexpr (OUTM == 10) {
        // XCD row-panel swizzle: grid (128,4); 4 consecutive same-XCD blocks
        // share one 1MB A row-panel -> L2-resident reuse (A fetch /4).
        const int fid = by * gridDim.x + bx;
        const int xcd = fid & 7, k = fid >> 3;   // k in 0..63
        bx = xcd * 16 + (k >> 2);
        by = k & 3;
    }
    const int row0 = bx * 64;
    const int col0 = by * 128;
    const int wr = (w >> 1) * 32;
    const int wc = (w & 1) * 64;
    const int grow = l >> 3;           // row within 8-row group
    const int gch = (l & 7) ^ grow;    // pre-swizzled k-chunk for gload_lds

    f32x4 acc[2][4];
#pragma unroll
    for (int mi = 0; mi < 2; ++mi)
#pragma unroll
        for (int ni = 0; ni < 4; ++ni)
#pragma unroll
            for (int j = 0; j < 4; ++j) acc[mi][ni][j] = 0.f;

    // AMODE==2: reg-staged A with fused per-(row, k-block) scale
    uint4 areg0, areg1; float ascl0, ascl1;
    auto ldA = [&](int k0) {
        const int r0 = w * 16 + grow, r1 = r0 + 8;
        const int scl = l & 7;
        areg0 = *(const uint4*)&Ah[(long)(row0 + r0) * lda + k0 + scl * 8];
        areg1 = *(const uint4*)&Ah[(long)(row0 + r1) * lda + k0 + scl * 8];
        const int e = k0 >> 9;
        ascl0 = wscale[(long)(row0 + r0) * 16 + e];
        ascl1 = wscale[(long)(row0 + r1) * 16 + e];
    };
    auto wrA = [&]() {
        const int scl = l & 7;
#pragma unroll
        for (int h = 0; h < 2; ++h) {
            const int r = w * 16 + grow + h * 8;
            const float s = h ? ascl1 : ascl0;
            f16x8 v = h ? *(f16x8*)&areg1 : *(f16x8*)&areg0;
#pragma unroll
            for (int j = 0; j < 8; ++j) v[j] = (f16)((float)v[j] * s);
            *(uint4*)&As[0][r][(scl ^ (r & 7)) * 8] = *(uint4*)&v;
        }
    };

    if constexpr (AMODE == 2) ldA(0);
    for (int k0 = 0; k0 < K; k0 += 64) {
        __syncthreads();
        if constexpr (AMODE == 2) {
            wrA();
            if (k0 + 64 < K) ldA(k0 + 64);  // next loads issued early (hidden under compute)
        } else {
            // A: wave w stages rows [w*16, w*16+16)
            const long ga = (long)(row0 + w * 16 + grow) * lda + k0 + gch * 8;
            gload16(Ah + ga, &As[0][w * 16][0]);
            gload16(Ah + ga + (long)8 * lda, &As[0][w * 16 + 8][0]);
            if constexpr (AMODE == 0) {
                gload16(Al + ga, &As[1][w * 16][0]);
                gload16(Al + ga + (long)8 * lda, &As[1][w * 16 + 8][0]);
            }
        }
        {
            // B: wave w stages rows [w*32, w*32+32)
            const long gb = (long)(col0 + w * 32 + grow) * ldb + k0 + gch * 8;
            gload16(Bh + gb, &Bs[0][w * 32][0]);
            gload16(Bh + gb + (long)8 * ldb, &Bs[0][w * 32 + 8][0]);
            gload16(Bh + gb + (long)16 * ldb, &Bs[0][w * 32 + 16][0]);
            gload16(Bh + gb + (long)24 * ldb, &Bs[0][w * 32 + 24][0]);
            if constexpr (!BSINGLE) {
                gload16(Bl + gb, &Bs[1][w * 32][0]);
                gload16(Bl + gb + (long)8 * ldb, &Bs[1][w * 32 + 8][0]);
                gload16(Bl + gb + (long)16 * ldb, &Bs[1][w * 32 + 16][0]);
                gload16(Bl + gb + (long)24 * ldb, &Bs[1][w * 32 + 24][0]);
            }
        }
        __syncthreads();
        const int r16 = l & 15, kg = l >> 4;
#pragma unroll
        for (int ks = 0; ks < 2; ++ks) {
            f16x8 a_h[2], a_l[2], b_h[4], b_l[4];
#pragma unroll
            for (int mi = 0; mi < 2; ++mi) {
                const int r = wr + mi * 16 + r16;
                const int off = ((ks * 4 + kg) ^ (r & 7)) * 8;
                a_h[mi] = *(const f16x8*)&As[0][r][off];
                if constexpr (AMODE == 0) a_l[mi] = *(const f16x8*)&As[1][r][off];
            }
#pragma unroll
            for (int ni = 0; ni < 4; ++ni) {
                const int c = wc + ni * 16 + r16;
                const int off = ((ks * 4 + kg) ^ (c & 7)) * 8;
                b_h[ni] = *(const f16x8*)&Bs[0][c][off];
                if constexpr (!BSINGLE) b_l[ni] = *(const f16x8*)&Bs[1][c][off];
            }
#pragma unroll
            for (int mi = 0; mi < 2; ++mi)
#pragma unroll
                for (int ni = 0; ni < 4; ++ni) {
                    acc[mi][ni] = __builtin_amdgcn_mfma_f32_16x16x32_f16(a_h[mi], b_h[ni], acc[mi][ni], 0, 0, 0);
                    if constexpr (!BSINGLE)
                        acc[mi][ni] = __builtin_amdgcn_mfma_f32_16x16x32_f16(a_h[mi], b_l[ni], acc[mi][ni], 0, 0, 0);
                    if constexpr (AMODE == 0)
                        acc[mi][ni] = __builtin_amdgcn_mfma_f32_16x16x32_f16(a_l[mi], b_h[ni], acc[mi][ni], 0, 0, 0);
                }
        }
    }
    // epilogue. C layout (m89-verified): col = lane&15, row = (lane>>4)*4 + reg.
    const int lane15 = l & 15;
    const int rsub = (l >> 4) * 4;
    if (OUTM == 5) {
        const int expert = col0 >> 9;
        float bv[4];
#pragma unroll
        for (int ni = 0; ni < 4; ++ni)
            bv[ni] = bias ? bias[col0 + wc + ni * 16 + lane15] : 0.f;
#pragma unroll
        for (int mi = 0; mi < 2; ++mi)
#pragma unroll
            for (int j = 0; j < 4; ++j) {
                const int rowg = row0 + wr + mi * 16 + rsub + j;
                const int t = task[rowg];
                const float* kqr = KQ2 + ((long)t * 16 + expert) * 512;
                float part = 0.f;
#pragma unroll
                for (int ni = 0; ni < 4; ++ni) {
                    const int colg = col0 + wc + ni * 16 + lane15;
                    float v = acc[mi][ni][j] + bv[ni];
                    if (RELU) v = fmaxf(v, 0.f);
                    Ch[(long)rowg * ldc + colg] = (f16)v;
                    part += v * kqr[colg & 511];
                }
#pragma unroll
                for (int d = 1; d < 16; d <<= 1) part += __shfl_xor(part, d);
                if (lane15 == 0) atomicAdd(&scores[rowg * 16 + expert], part);
            }
    } else {
        float* Cf2 = (float*)Cl;  // OUTM==10 partition-1 output
#pragma unroll
        for (int mi = 0; mi < 2; ++mi)
#pragma unroll
            for (int ni = 0; ni < 4; ++ni) {
                const int colg = col0 + wc + ni * 16 + lane15;
                const float bv = bias ? bias[colg] : 0.f;
#pragma unroll
                for (int j = 0; j < 4; ++j) {
                    const int rowg = row0 + wr + mi * 16 + rsub + j;
                    float v = acc[mi][ni][j] + bv;
                    if (RELU) v = fmaxf(v, 0.f);
                    if (OUTM == 0) {
                        f16 hh, ll; fsplit(v, hh, ll);
                        const long idx = (long)rowg * ldc + colg;
                        Ch[idx] = hh; Cl[idx] = ll;
                    } else if (OUTM == 1) {
                        f16 hh, ll; fsplit(v, hh, ll);
                        const long idx = (long)colg * ldc + rowg;
                        Ch[idx] = hh; Cl[idx] = ll;
                    } else if (OUTM == 2) {
                        Cf[(long)rowg * ldc + colg] = v;
                    } else if (OUTM == 3) {
                        Cf[(long)rowg * ldc + colg] += v;
                    } else if (OUTM == 6) {
                        Cf[(long)colg * ldc + rowg] = v;
                    } else if (OUTM == 7) {
                        Ch[(long)colg * ldc + rowg] = (f16)v;
                    } else if (OUTM == 9) {
                        Ch[(long)rowg * ldc + colg] = (f16)v;
                    } else if (OUTM == 10) {
                        const long idx = (long)rowg * ldc + colg;
                        if (z == 0) Cf[idx] = v;    // tiles disjoint per partition
                        else Cf2[idx] = v;
                    }
                }
            }
    }
}

// --- softmax over E=16 per row; adds cb[task[b]] (scores pre-zeroed) -------
__global__ void softmax16(float* __restrict__ sc, const int* __restrict__ task,
                          const float* __restrict__ cb) {
    const int b = blockIdx.x * 256 + threadIdx.x;  // 8192
    const float* cbr = cb + task[b] * 16;
    float v[16];
    const float4* pp = (const float4*)&sc[b * 16];
    const float4* cp = (const float4*)cbr;
#pragma unroll
    for (int qq = 0; qq < 4; ++qq) {
        float4 t = pp[qq];
        float4 c = cp[qq];
        v[qq * 4] = t.x + c.x; v[qq * 4 + 1] = t.y + c.y;
        v[qq * 4 + 2] = t.z + c.z; v[qq * 4 + 3] = t.w + c.w;
    }
    float m = v[0];
#pragma unroll
    for (int e = 1; e < 16; ++e) m = fmaxf(m, v[e]);
    float ssum = 0.f;
#pragma unroll
    for (int e = 0; e < 16; ++e) { v[e] = expf(v[e] - m); ssum += v[e]; }
    const float inv = 1.f / ssum;
    float4* o = (float4*)&sc[b * 16];
#pragma unroll
    for (int qq = 0; qq < 4; ++qq) {
        float4 t;
        t.x = v[qq * 4] * inv; t.y = v[qq * 4 + 1] * inv;
        t.z = v[qq * 4 + 2] * inv; t.w = v[qq * 4 + 3] * inv;
        o[qq] = t;
    }
}

// --- final heads: GEMV vs W2T (float4 streams), squash, logp ---------------
// Rcat: [8192][1024] single f16; cols 0..511 = mu path, 512..1023 = ls path.
__global__ void head_kernel2(
    const f16* __restrict__ Rh,
    const float* __restrict__ W2T,   // [2][32][512]
    const float* __restrict__ mb2, const float* __restrict__ lb2,
    const float* __restrict__ eps, float* __restrict__ pi, float* __restrict__ logp) {
    __shared__ float src[4][1032];
    const int tid = threadIdx.x, l = tid & 63, w = tid >> 6;
    const int b = blockIdx.x * 4 + w;  // one wave per row
    const long rb = (long)b * 1024;
    {
        f16x8 h0 = *(const f16x8*)&Rh[rb + l * 8];
        f16x8 h1 = *(const f16x8*)&Rh[rb + 512 + l * 8];
#pragma unroll
        for (int j = 0; j < 8; ++j) {
            src[w][l * 8 + j] = (float)h0[j];
            src[w][512 + l * 8 + j] = (float)h1[j];
        }
    }
    __syncthreads();
    const int col = l & 31;
    const int half = l >> 5;  // 0 = mu, 1 = log_std
    const float4* wp = (const float4*)(W2T + ((long)(half * 32 + col)) * 512);
    const float4* sp = (const float4*)(&src[w][half * 512]);
    float a0 = 0.f, a1 = 0.f, a2 = 0.f, a3 = 0.f;
#pragma unroll 8
    for (int k4 = 0; k4 < 128; ++k4) {
        const float4 wv = wp[k4];
        const float4 sv = sp[k4];
        a0 = fmaf(wv.x, sv.x, a0);
        a1 = fmaf(wv.y, sv.y, a1);
        a2 = fmaf(wv.z, sv.z, a2);
        a3 = fmaf(wv.w, sv.w, a3);
    }
    const float* b2 = half ? lb2 : mb2;
    float s = b2[col] + ((a0 + a1) + (a2 + a3));
    const float other = __shfl_xor(s, 32);  // swap mu <-> log_std halves
    if (half == 0) {
        const float mu = s;
        float ls = fminf(fmaxf(other, -20.f), 2.f);
        const float e = eps[(long)b * 32 + col];
        const float a = mu + expf(ls) * e;
        float lt = -0.5f * e * e - ls - 0.91893853320467274f;  // -0.5*log(2*pi)
        const float x = -2.f * a;
        const float sp2 = fmaxf(x, 0.f) + log1pf(expf(-fabsf(x)));
        lt -= 2.f * (0.69314718055994531f - a - sp2);
        pi[(long)b * 32 + col] = tanhf(a);
        float r = lt;
#pragma unroll
        for (int d = 1; d < 32; d <<= 1) r += __shfl_xor(r, d);
        if (col == 0) logp[b] = r;
    }
}

// ---------------------------------------------------------------------------
extern "C" void kernel_launch(void* const* d_in, const int* in_sizes, int n_in,
                              void* d_out, int out_size, void* d_ws, size_t ws_size,
                              hipStream_t stream) {
    const float* obs = (const float*)d_in[0];
    const int* task = (const int*)d_in[1];
    const float* eps = (const float*)d_in[2];
    const float* bW1 = (const float*)d_in[3];
    const float* bb1 = (const float*)d_in[4];
    const float* bW2 = (const float*)d_in[5];
    const float* bb2 = (const float*)d_in[6];
    const float* eW1 = (const float*)d_in[7];
    const float* eb1 = (const float*)d_in[8];
    const float* eW2 = (const float*)d_in[9];
    const float* eb2 = (const float*)d_in[10];
    const float* keyM = (const float*)d_in[11];
    const float* valM = (const float*)d_in[12];
    const float* tq = (const float*)d_in[13];
    const float* mW1 = (const float*)d_in[14];
    const float* mb1 = (const float*)d_in[15];
    const float* mW2 = (const float*)d_in[16];
    const float* mb2 = (const float*)d_in[17];
    const float* lW1 = (const float*)d_in[18];
    const float* lb1 = (const float*)d_in[19];
    const float* lW2 = (const float*)d_in[20];
    const float* lb2 = (const float*)d_in[21];
    (void)in_sizes; (void)n_in; (void)out_size; (void)ws_size;

    // ---- workspace map (base 122 MB + 128 MB U; ws >= 251 MB verified R4) --
    const size_t MB = 1u << 20, KB = 1u << 10;
    char* base = (char*)d_ws;
    f16* eW1t_h = (f16*)(base + 0 * MB);   f16* eW1t_l = (f16*)(base + 8 * MB);
    f16* Wv2_h  = (f16*)(base + 16 * MB);  // [j2][(e,i)] single f16
    f16* eW2s_h = (f16*)(base + 32 * MB);  f16* eW2s_l = (f16*)(base + 40 * MB);
    f16* h2_h   = (f16*)(base + 32 * MB);  f16* h2_l   = (f16*)(base + 40 * MB);  // after folds
    f16* t1_h   = (f16*)(base + 48 * MB);  f16* t1_l   = (f16*)(base + 56 * MB);
    f16* Rcat   = (f16*)(base + 48 * MB);                                         // heads (t1 dead), 16 MB single
    f16* Vt_h   = (f16*)(base + 64 * MB);  f16* Vt_l   = (f16*)(base + 72 * MB);
    float* towerAcc2 = (float*)(base + 64 * MB);                                  // phase 2 (Vt dead), 16 MB
    // 80-112 MB region, phase 1 (KQ path): keyM pairs, KqT, tqP, KQ2
    f16* keyMs_h = (f16*)(base + 80 * MB); f16* keyMs_l = (f16*)(base + 88 * MB);
    f16* KqT_h   = (f16*)(base + 96 * MB); f16* KqT_l   = (f16*)(base + 98 * MB); // [128][8192]
    f16* tqP_h   = (f16*)(base + 100 * MB); f16* tqP_l  = (f16*)(base + 100 * MB + 128 * KB); // [128][512]
    float* KQ2   = (float*)(base + 104 * MB);                                     // [128][16][512] f32
    // 80-112 MB region, phase 2 (tower/heads): towerAcc, twP (single)
    float* towerAcc = (float*)(base + 80 * MB);                                   // 16 MB
    f16* twP_h  = (f16*)(base + 96 * MB);
    f16* obs_h  = (f16*)(base + 112 * MB); f16* obs_l  = (f16*)(base + 114 * MB);
    char* q = base + 116 * MB;
    f16* bW1t_h = (f16*)q; q += 128 * KB;  f16* bW1t_l = (f16*)q; q += 128 * KB;
    f16* bW2t_h = (f16*)q; q += 512 * KB;  f16* bW2t_l = (f16*)q; q += 512 * KB;
    // order m_h, l_h, m_l, l_l so the z=2 head GEMM can stride (zsB = 262144)
    f16* mW1t_h = (f16*)q; q += 512 * KB;
    f16* lW1t_h = (f16*)q; q += 512 * KB;
    f16* mW1t_l = (f16*)q; q += 512 * KB;
    f16* lW1t_l = (f16*)q; q += 512 * KB;
    float* scores = (float*)q; q += 512 * KB;    // 8192*16 f32 (becomes w)
    float* b2V    = (float*)q; q += 32 * KB;
    float* cb     = (float*)q; q += 16 * KB;
    float* W2T    = (float*)q; q += 128 * KB;    // [2][32][512]
    float* bcat   = (float*)q; q += 16 * KB;     // [2][512]
    f16* U = (f16*)(base + 122 * MB);            // [8192][8192] single f16

    const long EST = 262144;  // per-expert 512x512 stride

    // ---- 1) splits / transposes ----
    hipMemsetAsync(tqP_h, 0, 256 * KB, stream);   // tqP_h and tqP_l contiguous
    hipMemsetAsync(scores, 0, 512 * KB, stream);  // passA atomicAdd target
    split_pairs4<<<9241, 256, 0, stream>>>(eW2, eW2s_h, eW2s_l, keyM, keyMs_h, keyMs_l,
                                           obs, obs_h, obs_l, tq, tqP_h, tqP_l);
    transpose_split6<<<dim3(16, 16, 36), 256, 0, stream>>>(
        eW1, valM, bW2, mW1, lW1, bW1, eW1t_h, eW1t_l, Vt_h, Vt_l,
        bW2t_h, bW2t_l, mW1t_h, mW1t_l, lW1t_h, lW1t_l, bW1t_h, bW1t_l);
    build_w2t_bcat<<<132, 256, 0, stream>>>(mW2, lW2, mb1, lb1, W2T, bcat);

    // ---- 2) attention folds ----
    // Wv2[j2][(e,i)] = (eW2@V)[i][j2]  (single-f16 out -> 2-MFMA: A pair x B single)
    gemm_pair<7, false, 0, true><<<dim3(8, 4, 16), 256, 0, stream>>>(
        eW2s_h, eW2s_l, 512, EST, Vt_h, nullptr, 512, EST, nullptr, 0,
        Wv2_h, nullptr, nullptr, 8192, 512, 512, nullptr, nullptr, nullptr, nullptr);
    // KqT[t][(e,k)] = (keyM @ tq^T)[(e,k)][t]   (N=128 padded, pair transposed)
    gemm_pair<1, false, 0, false><<<dim3(128, 1, 1), 256, 0, stream>>>(
        keyMs_h, keyMs_l, 512, 0, tqP_h, tqP_l, 512, 0, nullptr, 0,
        KqT_h, KqT_l, nullptr, 8192, 0, 512, nullptr, nullptr, nullptr, nullptr);
    // KQ2[(t,e)][i] = (eW2_e @ KqT_e^T)[i][t]   (f32 transposed write)
    gemm_pair<6, false, 0, false><<<dim3(8, 1, 16), 256, 0, stream>>>(
        eW2s_h, eW2s_l, 512, EST, KqT_h, KqT_l, 8192, 512, nullptr, 0,
        nullptr, nullptr, KQ2, 8192, 512, 512, nullptr, nullptr, nullptr, nullptr);
    fold_misc<<<232, 256, 0, stream>>>(eb2, valM, KqT_h, KqT_l, b2V, cb);

    // ---- 3) backbone (full pair precision: feeds the score path) ----
    gemm_pair<0, true, 0, false><<<dim3(128, 4, 1), 256, 0, stream>>>(
        obs_h, obs_l, 128, 0, bW1t_h, bW1t_l, 128, 0, bb1, 0,
        t1_h, t1_l, nullptr, 512, 0, 128, nullptr, nullptr, nullptr, nullptr);
    gemm_pair<0, true, 0, false><<<dim3(128, 4, 1), 256, 0, stream>>>(
        t1_h, t1_l, 512, 0, bW2t_h, bW2t_l, 512, 0, bb2, 0,
        h2_h, h2_l, nullptr, 512, 0, 512, nullptr, nullptr, nullptr, nullptr);

    // ---- 4) pass A: one flat M=8192 x N=8192 GEMM; scores + U ----
    gemm_pair<5, true, 0, false><<<dim3(128, 64, 1), 256, 0, stream>>>(
        h2_h, h2_l, 512, 0, eW1t_h, eW1t_l, 512, 0, eb1, 0,
        U, nullptr, nullptr, 8192, 0, 512, nullptr, task, KQ2, scores);
    softmax16<<<32, 256, 0, stream>>>(scores, task, cb);

    // ---- 5) tower: split-K=2 plain writes (z=0 -> towerAcc, z=1 ->
    //         towerAcc2); tw_finish sums partials + wb and converts to f16 ----
    gemm_pair<10, false, 2, true><<<dim3(128, 4, 2), 256, 0, stream>>>(
        U, nullptr, 8192, 4096, Wv2_h, nullptr, 8192, 4096, nullptr, 0,
        nullptr, (f16*)towerAcc2, towerAcc, 512, 0, 4096, scores, nullptr, nullptr, nullptr);
    tw_finish<<<4096, 256, 0, stream>>>(towerAcc, towerAcc2, scores, b2V, twP_h);

    // ---- 6) heads: layer-1 (single x single = 1 MFMA) into Rcat, GEMV+squash --
    gemm_pair<9, true, 1, true><<<dim3(128, 4, 2), 256, 0, stream>>>(
        twP_h, nullptr, 512, 0, mW1t_h, nullptr, 512, 262144, bcat, 512,
        Rcat, nullptr, nullptr, 1024, 512, 512, nullptr, nullptr, nullptr, nullptr);
    head_kernel2<<<2048, 256, 0, stream>>>(Rcat, W2T, mb2, lb2, eps,
                                           (float*)d_out, (float*)d_out + 262144);
}